// Round 1
// baseline (1176.926 us; speedup 1.0000x reference)
//
#include <hip/hip_runtime.h>
#include <hip/hip_bf16.h>

// GraphTransformerLayer on MI355X — round 1: correctness-first fp32.
// N=50000 nodes, E=500000 edges, D=128, H=8, DH=16.

#define D_ 128
#define GKCH 64   // K-chunk staged in LDS

// ---------------------------------------------------------------------------
// Generic GEMM: C[n x M] = A[n x K] @ W[M x K]^T (+ bias) (+ relu)
// Block: 256 threads, computes 32 rows x 128 cols. Micro-tile 4x4.
// LDS layout transposed (k-major) so inner loop reads are float4.
// ---------------------------------------------------------------------------
template<bool RELU>
__global__ __launch_bounds__(256) void gemm_kernel(
    const float* __restrict__ A, const float* __restrict__ W,
    const float* __restrict__ bias, float* __restrict__ C,
    int n, int K, int M)
{
    __shared__ float As[GKCH][36];   // [k][row0..31], pad->36 keeps float4 align (144B row)
    __shared__ float Ws[GKCH][132];  // [k][col0..127], pad->132 (528B row, 16B aligned)

    const int t  = threadIdx.x;
    const int r0 = blockIdx.x * 32;
    const int c0 = blockIdx.y * 128;
    const int ry = t >> 5;   // 0..7  (row group, 4 rows each)
    const int cy = t & 31;   // 0..31 (col group, 4 cols each)

    float acc[4][4] = {};

    for (int kc = 0; kc < K; kc += GKCH) {
        // stage A chunk: 32 rows x 64 ks = 512 float4, 2 per thread
        #pragma unroll
        for (int rep = 0; rep < 2; ++rep) {
            int i   = t + rep * 256;      // [0,512)
            int row = i >> 4;             // 16 float4 per row
            int k4  = i & 15;
            int gr  = r0 + row;
            float4 a4 = make_float4(0.f, 0.f, 0.f, 0.f);
            if (gr < n)
                a4 = *reinterpret_cast<const float4*>(A + (size_t)gr * K + kc + k4 * 4);
            As[k4*4+0][row] = a4.x;
            As[k4*4+1][row] = a4.y;
            As[k4*4+2][row] = a4.z;
            As[k4*4+3][row] = a4.w;
        }
        // stage W chunk: 128 cols x 64 ks = 2048 float4, 8 per thread
        #pragma unroll
        for (int rep = 0; rep < 8; ++rep) {
            int i   = t + rep * 256;      // [0,2048)
            int col = i >> 4;
            int k4  = i & 15;
            float4 w4 = *reinterpret_cast<const float4*>(
                W + (size_t)(c0 + col) * K + kc + k4 * 4);
            Ws[k4*4+0][col] = w4.x;
            Ws[k4*4+1][col] = w4.y;
            Ws[k4*4+2][col] = w4.z;
            Ws[k4*4+3][col] = w4.w;
        }
        __syncthreads();

        #pragma unroll
        for (int k = 0; k < GKCH; ++k) {
            float4 av = *reinterpret_cast<const float4*>(&As[k][ry * 4]);
            float4 wv = *reinterpret_cast<const float4*>(&Ws[k][cy * 4]);
            float a_[4] = {av.x, av.y, av.z, av.w};
            float w_[4] = {wv.x, wv.y, wv.z, wv.w};
            #pragma unroll
            for (int i2 = 0; i2 < 4; ++i2)
                #pragma unroll
                for (int j = 0; j < 4; ++j)
                    acc[i2][j] = fmaf(a_[i2], w_[j], acc[i2][j]);
        }
        __syncthreads();
    }

    float4 b4 = make_float4(0.f, 0.f, 0.f, 0.f);
    if (bias) b4 = *reinterpret_cast<const float4*>(bias + c0 + cy * 4);
    #pragma unroll
    for (int i2 = 0; i2 < 4; ++i2) {
        int gr = r0 + ry * 4 + i2;
        if (gr >= n) break;
        float4 o4;
        o4.x = acc[i2][0] + b4.x;
        o4.y = acc[i2][1] + b4.y;
        o4.z = acc[i2][2] + b4.z;
        o4.w = acc[i2][3] + b4.w;
        if (RELU) {
            o4.x = fmaxf(o4.x, 0.f); o4.y = fmaxf(o4.y, 0.f);
            o4.z = fmaxf(o4.z, 0.f); o4.w = fmaxf(o4.w, 0.f);
        }
        *reinterpret_cast<float4*>(C + (size_t)gr * M + c0 + cy * 4) = o4;
    }
}

// ---------------------------------------------------------------------------
// out = LayerNorm(a + b) over D=128. One 64-lane wave per row, 2 cols/lane.
// ---------------------------------------------------------------------------
__global__ __launch_bounds__(256) void ln_residual_kernel(
    const float* __restrict__ a, const float* __restrict__ b,
    const float* __restrict__ g, const float* __restrict__ be,
    float* __restrict__ out, int n)
{
    int wid  = (blockIdx.x * blockDim.x + threadIdx.x) >> 6;
    int lane = threadIdx.x & 63;
    if (wid >= n) return;
    float2 av = reinterpret_cast<const float2*>(a + (size_t)wid * D_)[lane];
    float2 bv = reinterpret_cast<const float2*>(b + (size_t)wid * D_)[lane];
    float x0 = av.x + bv.x, x1 = av.y + bv.y;
    float s  = x0 + x1;
    float s2 = x0 * x0 + x1 * x1;
    #pragma unroll
    for (int o = 1; o < 64; o <<= 1) {
        s  += __shfl_xor(s,  o);
        s2 += __shfl_xor(s2, o);
    }
    float m   = s * (1.f / 128.f);
    float var = s2 * (1.f / 128.f) - m * m;
    float rs  = rsqrtf(var + 1e-5f);
    float2 gv  = reinterpret_cast<const float2*>(g)[lane];
    float2 bev = reinterpret_cast<const float2*>(be)[lane];
    float2 o2;
    o2.x = (x0 - m) * rs * gv.x + bev.x;
    o2.y = (x1 - m) * rs * gv.y + bev.y;
    reinterpret_cast<float2*>(out + (size_t)wid * D_)[lane] = o2;
}

// ---------------------------------------------------------------------------
// Edge attention scatter. One wave per edge; lane handles 2 channels.
// Head h = lane>>3 (8 lanes * 2 ch = 16 dims). Scatter via fp32 atomics.
// ---------------------------------------------------------------------------
__global__ __launch_bounds__(256) void edge_attn_kernel(
    const int* __restrict__ src, const int* __restrict__ dst,
    const float* __restrict__ Q, const float* __restrict__ K,
    const float* __restrict__ V,
    float* __restrict__ wV, float* __restrict__ z, int E_)
{
    int e = (blockIdx.x * blockDim.x + threadIdx.x) >> 6;
    if (e >= E_) return;
    int lane = threadIdx.x & 63;
    int s = src[e], d = dst[e];
    float2 kv = reinterpret_cast<const float2*>(K + (size_t)s * D_)[lane];
    float2 qv = reinterpret_cast<const float2*>(Q + (size_t)d * D_)[lane];
    float p = kv.x * qv.x + kv.y * qv.y;
    p += __shfl_xor(p, 1);
    p += __shfl_xor(p, 2);
    p += __shfl_xor(p, 4);           // now all 8 lanes of the head group hold the dot
    float sc = p * 0.25f;            // / sqrt(16)
    sc = fminf(fmaxf(sc, -5.f), 5.f);
    sc = expf(sc);
    float2 vv = reinterpret_cast<const float2*>(V + (size_t)s * D_)[lane];
    atomicAdd(wV + (size_t)d * D_ + lane * 2 + 0, vv.x * sc);
    atomicAdd(wV + (size_t)d * D_ + lane * 2 + 1, vv.y * sc);
    if ((lane & 7) == 0)
        atomicAdd(z + (size_t)d * 8 + (lane >> 3), sc);
}

// y = hsub + wV/z (per-head z)
__global__ void add_attn_kernel(const float* __restrict__ hsub,
                                const float* __restrict__ wV,
                                const float* __restrict__ z,
                                float* __restrict__ y, int total)
{
    int i = blockIdx.x * blockDim.x + threadIdx.x;
    if (i >= total) return;
    int row = i >> 7, c = i & 127;
    y[i] = hsub[i] + wV[i] / z[row * 8 + (c >> 4)];
}

// y = a + b
__global__ void add_kernel(const float* __restrict__ a, const float* __restrict__ b,
                           float* __restrict__ y, int total)
{
    int i = blockIdx.x * blockDim.x + threadIdx.x;
    if (i >= total) return;
    y[i] = a[i] + b[i];
}

// Per-channel sum / sumsq over the batch: sums[c], sums[128+c].
__global__ __launch_bounds__(256) void bn_stats_kernel(
    const float* __restrict__ x, float* __restrict__ sums, int n)
{
    int c    = threadIdx.x & 127;
    int half = threadIdx.x >> 7;    // 0/1
    float s = 0.f, s2 = 0.f;
    for (int r = blockIdx.x * 2 + half; r < n; r += gridDim.x * 2) {
        float v = x[(size_t)r * D_ + c];
        s += v; s2 += v * v;
    }
    __shared__ float ls[256], ls2[256];
    ls[threadIdx.x] = s; ls2[threadIdx.x] = s2;
    __syncthreads();
    if (half == 0) {
        s  += ls[threadIdx.x + 128];
        s2 += ls2[threadIdx.x + 128];
        atomicAdd(sums + c, s);
        atomicAdd(sums + 128 + c, s2);
    }
}

__global__ void bn_norm_kernel(const float* __restrict__ x,
                               const float* __restrict__ stats,
                               const float* __restrict__ g, const float* __restrict__ b,
                               float* __restrict__ out, int n, int total)
{
    int i = blockIdx.x * blockDim.x + threadIdx.x;
    if (i >= total) return;
    int c = i & 127;
    float invn = 1.f / (float)n;
    float m   = stats[c] * invn;
    float var = stats[128 + c] * invn - m * m;
    float rs  = rsqrtf(var + 1e-5f);
    out[i] = (x[i] - m) * rs * g[c] + b[c];
}

// ---------------------------------------------------------------------------
extern "C" void kernel_launch(void* const* d_in, const int* in_sizes, int n_in,
                              void* d_out, int out_size, void* d_ws, size_t ws_size,
                              hipStream_t stream)
{
    const float* h    = (const float*)d_in[0];
    const int*   src  = (const int*)d_in[1];
    const int*   dst  = (const int*)d_in[2];
    const float* Win  = (const float*)d_in[3];
    const float* bin_ = (const float*)d_in[4];
    const float* Wout = (const float*)d_in[5];
    const float* bout = (const float*)d_in[6];
    const float* Wte1 = (const float*)d_in[7];
    const float* bte1 = (const float*)d_in[8];
    const float* Wte2 = (const float*)d_in[9];
    const float* bte2 = (const float*)d_in[10];
    const float* ln1g = (const float*)d_in[11];
    const float* ln1b = (const float*)d_in[12];
    const float* ln2g = (const float*)d_in[13];
    const float* ln2b = (const float*)d_in[14];
    const float* WQ   = (const float*)d_in[15];
    const float* WK   = (const float*)d_in[16];
    const float* WV   = (const float*)d_in[17];
    const float* W1   = (const float*)d_in[18];
    const float* b1   = (const float*)d_in[19];
    const float* W2   = (const float*)d_in[20];
    const float* b2   = (const float*)d_in[21];
    const float* bn1g = (const float*)d_in[22];
    const float* bn1b = (const float*)d_in[23];
    const float* bn2g = (const float*)d_in[24];
    const float* bn2b = (const float*)d_in[25];

    const int N_ = in_sizes[0] / D_;
    const int E_ = in_sizes[1];
    const size_t S = (size_t)N_ * D_;

    float* ws = (float*)d_ws;
    if (ws_size < (6 * S + 512) * sizeof(float)) return;  // need ~154MB
    float* bufA  = ws;            // S
    float* bufB  = ws + S;        // S
    float* bufC  = ws + 2 * S;    // 4S
    float* stats = ws + 6 * S;    // 512

    dim3 blk(256);
    const int rowChunks = (N_ + 31) / 32;
    const int totElems  = N_ * D_;
    const dim3 gElem((totElems + 255) / 256);
    const dim3 gRow((N_ + 3) / 4);

    hipMemsetAsync(stats, 0, 512 * sizeof(float), stream);

    // --- per-node TransformerEncoder (seq_len==1 => attn_out = out_proj(V)) ---
    // v = h @ WinV^T + binV   (V slice = rows [256,384) of Win)
    gemm_kernel<false><<<dim3(rowChunks, 1), blk, 0, stream>>>(
        h, Win + 256 * 128, bin_ + 256, bufA, N_, 128, 128);
    // t = v @ Wout^T + bout
    gemm_kernel<false><<<dim3(rowChunks, 1), blk, 0, stream>>>(
        bufA, Wout, bout, bufB, N_, 128, 128);
    // x = LN(h + t)  (in place over t)
    ln_residual_kernel<<<gRow, blk, 0, stream>>>(h, bufB, ln1g, ln1b, bufB, N_);
    // ff1 = relu(x @ Wte1^T + bte1)   [N,512]
    gemm_kernel<true><<<dim3(rowChunks, 4), blk, 0, stream>>>(
        bufB, Wte1, bte1, bufC, N_, 128, 512);
    // ff = ff1 @ Wte2^T + bte2
    gemm_kernel<false><<<dim3(rowChunks, 1), blk, 0, stream>>>(
        bufC, Wte2, bte2, bufA, N_, 512, 128);
    // hsub = LN(x + ff) -> bufC[0:S]
    float* hsub = bufC;
    ln_residual_kernel<<<gRow, blk, 0, stream>>>(bufB, bufA, ln2g, ln2b, hsub, N_);

    // --- graph multi-head attention ---
    gemm_kernel<false><<<dim3(rowChunks, 1), blk, 0, stream>>>(
        hsub, WQ, nullptr, bufA, N_, 128, 128);                  // Q
    gemm_kernel<false><<<dim3(rowChunks, 1), blk, 0, stream>>>(
        hsub, WK, nullptr, bufB, N_, 128, 128);                  // K
    float* Vbuf = bufC + S;
    gemm_kernel<false><<<dim3(rowChunks, 1), blk, 0, stream>>>(
        hsub, WV, nullptr, Vbuf, N_, 128, 128);                  // V
    float* wV   = bufC + 2 * S;
    float* zbuf = bufC + 3 * S;
    hipMemsetAsync(wV, 0, S * sizeof(float), stream);
    hipMemsetAsync(zbuf, 0, (size_t)N_ * 8 * sizeof(float), stream);
    edge_attn_kernel<<<dim3((E_ + 3) / 4), blk, 0, stream>>>(
        src, dst, bufA, bufB, Vbuf, wV, zbuf, E_);
    // y1 = hsub + wV/z -> bufA
    add_attn_kernel<<<gElem, blk, 0, stream>>>(hsub, wV, zbuf, bufA, totElems);

    // --- BN1 ---
    bn_stats_kernel<<<dim3(256), blk, 0, stream>>>(bufA, stats, N_);
    bn_norm_kernel<<<gElem, blk, 0, stream>>>(bufA, stats, bn1g, bn1b, bufB, N_, totElems); // hh

    // --- FFN + BN2 ---
    // f1 = relu(hh @ W1^T + b1)  [N,256] -> bufC[0:2S]
    gemm_kernel<true><<<dim3(rowChunks, 2), blk, 0, stream>>>(
        bufB, W1, b1, bufC, N_, 128, 256);
    // f2 = f1 @ W2^T + b2 -> bufC[2S:3S]
    gemm_kernel<false><<<dim3(rowChunks, 1), blk, 0, stream>>>(
        bufC, W2, b2, bufC + 2 * S, N_, 256, 128);
    // y2 = hh + f2 -> bufA
    add_kernel<<<gElem, blk, 0, stream>>>(bufB, bufC + 2 * S, bufA, totElems);
    bn_stats_kernel<<<dim3(256), blk, 0, stream>>>(bufA, stats + 256, N_);
    bn_norm_kernel<<<gElem, blk, 0, stream>>>(bufA, stats + 256, bn2g, bn2b,
                                              (float*)d_out, N_, totElems);
}

// Round 2
// 847.505 us; speedup vs baseline: 1.3887x; 1.3887x over previous
//
#include <hip/hip_runtime.h>
#include <hip/hip_bf16.h>

// GraphTransformerLayer on MI355X — round 2: CSR-gather edge attention.
// N=50000 nodes, E=500000 edges, D=128, H=8, DH=16.

#define D_ 128
#define GKCH 64   // GEMM K-chunk staged in LDS

// ---------------------------------------------------------------------------
// Generic GEMM: C[n x M] = A[n x K] @ W[M x K]^T (+ bias) (+ relu)
// Block: 256 threads, computes 32 rows x 128 cols. Micro-tile 4x4.
// ---------------------------------------------------------------------------
template<bool RELU>
__global__ __launch_bounds__(256) void gemm_kernel(
    const float* __restrict__ A, const float* __restrict__ W,
    const float* __restrict__ bias, float* __restrict__ C,
    int n, int K, int M)
{
    __shared__ float As[GKCH][36];
    __shared__ float Ws[GKCH][132];

    const int t  = threadIdx.x;
    const int r0 = blockIdx.x * 32;
    const int c0 = blockIdx.y * 128;
    const int ry = t >> 5;
    const int cy = t & 31;

    float acc[4][4] = {};

    for (int kc = 0; kc < K; kc += GKCH) {
        #pragma unroll
        for (int rep = 0; rep < 2; ++rep) {
            int i   = t + rep * 256;
            int row = i >> 4;
            int k4  = i & 15;
            int gr  = r0 + row;
            float4 a4 = make_float4(0.f, 0.f, 0.f, 0.f);
            if (gr < n)
                a4 = *reinterpret_cast<const float4*>(A + (size_t)gr * K + kc + k4 * 4);
            As[k4*4+0][row] = a4.x;
            As[k4*4+1][row] = a4.y;
            As[k4*4+2][row] = a4.z;
            As[k4*4+3][row] = a4.w;
        }
        #pragma unroll
        for (int rep = 0; rep < 8; ++rep) {
            int i   = t + rep * 256;
            int col = i >> 4;
            int k4  = i & 15;
            float4 w4 = *reinterpret_cast<const float4*>(
                W + (size_t)(c0 + col) * K + kc + k4 * 4);
            Ws[k4*4+0][col] = w4.x;
            Ws[k4*4+1][col] = w4.y;
            Ws[k4*4+2][col] = w4.z;
            Ws[k4*4+3][col] = w4.w;
        }
        __syncthreads();

        #pragma unroll
        for (int k = 0; k < GKCH; ++k) {
            float4 av = *reinterpret_cast<const float4*>(&As[k][ry * 4]);
            float4 wv = *reinterpret_cast<const float4*>(&Ws[k][cy * 4]);
            float a_[4] = {av.x, av.y, av.z, av.w};
            float w_[4] = {wv.x, wv.y, wv.z, wv.w};
            #pragma unroll
            for (int i2 = 0; i2 < 4; ++i2)
                #pragma unroll
                for (int j = 0; j < 4; ++j)
                    acc[i2][j] = fmaf(a_[i2], w_[j], acc[i2][j]);
        }
        __syncthreads();
    }

    float4 b4 = make_float4(0.f, 0.f, 0.f, 0.f);
    if (bias) b4 = *reinterpret_cast<const float4*>(bias + c0 + cy * 4);
    #pragma unroll
    for (int i2 = 0; i2 < 4; ++i2) {
        int gr = r0 + ry * 4 + i2;
        if (gr >= n) break;
        float4 o4;
        o4.x = acc[i2][0] + b4.x;
        o4.y = acc[i2][1] + b4.y;
        o4.z = acc[i2][2] + b4.z;
        o4.w = acc[i2][3] + b4.w;
        if (RELU) {
            o4.x = fmaxf(o4.x, 0.f); o4.y = fmaxf(o4.y, 0.f);
            o4.z = fmaxf(o4.z, 0.f); o4.w = fmaxf(o4.w, 0.f);
        }
        *reinterpret_cast<float4*>(C + (size_t)gr * M + c0 + cy * 4) = o4;
    }
}

// ---------------------------------------------------------------------------
// out = LayerNorm(a + b) over D=128. One wave per row, 2 cols/lane.
// ---------------------------------------------------------------------------
__global__ __launch_bounds__(256) void ln_residual_kernel(
    const float* __restrict__ a, const float* __restrict__ b,
    const float* __restrict__ g, const float* __restrict__ be,
    float* __restrict__ out, int n)
{
    int wid  = (blockIdx.x * blockDim.x + threadIdx.x) >> 6;
    int lane = threadIdx.x & 63;
    if (wid >= n) return;
    float2 av = reinterpret_cast<const float2*>(a + (size_t)wid * D_)[lane];
    float2 bv = reinterpret_cast<const float2*>(b + (size_t)wid * D_)[lane];
    float x0 = av.x + bv.x, x1 = av.y + bv.y;
    float s  = x0 + x1;
    float s2 = x0 * x0 + x1 * x1;
    #pragma unroll
    for (int o = 1; o < 64; o <<= 1) {
        s  += __shfl_xor(s,  o);
        s2 += __shfl_xor(s2, o);
    }
    float m   = s * (1.f / 128.f);
    float var = s2 * (1.f / 128.f) - m * m;
    float rs  = rsqrtf(var + 1e-5f);
    float2 gv  = reinterpret_cast<const float2*>(g)[lane];
    float2 bev = reinterpret_cast<const float2*>(be)[lane];
    float2 o2;
    o2.x = (x0 - m) * rs * gv.x + bev.x;
    o2.y = (x1 - m) * rs * gv.y + bev.y;
    reinterpret_cast<float2*>(out + (size_t)wid * D_)[lane] = o2;
}

// ---------------------------------------------------------------------------
// CSR build: histogram -> exclusive scan (3 small kernels) -> scatter.
// rowptr doubles as count buffer; after scatter rowptr[d] == inclusive end.
// ---------------------------------------------------------------------------
__global__ void hist_kernel(const int* __restrict__ dst, int* __restrict__ cnt, int E_)
{
    int e = blockIdx.x * blockDim.x + threadIdx.x;
    if (e < E_) atomicAdd(cnt + dst[e], 1);
}

// exclusive scan of each 256-chunk in place; block totals to bsum
__global__ __launch_bounds__(256) void scan_block_kernel(
    int* __restrict__ data, int* __restrict__ bsum, int n)
{
    __shared__ int tmp[256];
    int i = blockIdx.x * 256 + threadIdx.x;
    int v = (i < n) ? data[i] : 0;
    tmp[threadIdx.x] = v;
    __syncthreads();
    #pragma unroll
    for (int o = 1; o < 256; o <<= 1) {
        int y = (threadIdx.x >= o) ? tmp[threadIdx.x - o] : 0;
        __syncthreads();
        tmp[threadIdx.x] += y;
        __syncthreads();
    }
    if (i < n) data[i] = tmp[threadIdx.x] - v;      // exclusive
    if (threadIdx.x == 255) bsum[blockIdx.x] = tmp[255];
}

// exclusive scan of block sums (nb <= 256) in one block
__global__ __launch_bounds__(256) void scan_bsum_kernel(int* __restrict__ bsum, int nb)
{
    __shared__ int tmp[256];
    int v = (threadIdx.x < nb) ? bsum[threadIdx.x] : 0;
    tmp[threadIdx.x] = v;
    __syncthreads();
    #pragma unroll
    for (int o = 1; o < 256; o <<= 1) {
        int y = (threadIdx.x >= o) ? tmp[threadIdx.x - o] : 0;
        __syncthreads();
        tmp[threadIdx.x] += y;
        __syncthreads();
    }
    if (threadIdx.x < nb) bsum[threadIdx.x] = tmp[threadIdx.x] - v;
}

__global__ void add_off_kernel(int* __restrict__ data, const int* __restrict__ bsum, int n)
{
    int i = blockIdx.x * blockDim.x + threadIdx.x;
    if (i < n) data[i] += bsum[i >> 8];
}

__global__ void scatter_kernel(const int* __restrict__ src, const int* __restrict__ dst,
                               int* __restrict__ rowptr, int* __restrict__ csr_src, int E_)
{
    int e = blockIdx.x * blockDim.x + threadIdx.x;
    if (e >= E_) return;
    int pos = atomicAdd(rowptr + dst[e], 1);
    csr_src[pos] = src[e];
}

// ---------------------------------------------------------------------------
// Gather-side attention aggregation. One wave per node, 2 ch/lane, head = lane>>3.
// Writes y1 = hsub + wV/z directly (no atomics, fused residual).
// ---------------------------------------------------------------------------
__global__ __launch_bounds__(256) void attn_agg_kernel(
    const int* __restrict__ rowptr, const int* __restrict__ csr_src,
    const float* __restrict__ Q, const float* __restrict__ K,
    const float* __restrict__ V, const float* __restrict__ hsub,
    float* __restrict__ out, int n)
{
    int node = (blockIdx.x * blockDim.x + threadIdx.x) >> 6;
    if (node >= n) return;
    int lane = threadIdx.x & 63;
    int start = node ? rowptr[node - 1] : 0;
    int end   = rowptr[node];
    float2 q = reinterpret_cast<const float2*>(Q + (size_t)node * D_)[lane];
    float ax = 0.f, ay = 0.f, zh = 0.f;
    for (int j = start; j < end; ++j) {
        int s = csr_src[j];
        float2 kv = reinterpret_cast<const float2*>(K + (size_t)s * D_)[lane];
        float p = kv.x * q.x + kv.y * q.y;
        p += __shfl_xor(p, 1);
        p += __shfl_xor(p, 2);
        p += __shfl_xor(p, 4);          // 8-lane head-group dot
        float sc = __expf(fminf(fmaxf(p * 0.25f, -5.f), 5.f));
        float2 vv = reinterpret_cast<const float2*>(V + (size_t)s * D_)[lane];
        ax = fmaf(sc, vv.x, ax);
        ay = fmaf(sc, vv.y, ay);
        zh += sc;
    }
    float2 hv = reinterpret_cast<const float2*>(hsub + (size_t)node * D_)[lane];
    float inv = 1.f / zh;
    float2 o2;
    o2.x = hv.x + ax * inv;
    o2.y = hv.y + ay * inv;
    reinterpret_cast<float2*>(out + (size_t)node * D_)[lane] = o2;
}

// ---------------------------------------------------------------------------
// BN stats (optionally fusing y = a + b first). sums[c], sums[128+c].
// ---------------------------------------------------------------------------
template<bool ADD>
__global__ __launch_bounds__(256) void bn_stats_kernel(
    const float* __restrict__ a, const float* __restrict__ b,
    float* __restrict__ y, float* __restrict__ sums, int n)
{
    int c    = threadIdx.x & 127;
    int half = threadIdx.x >> 7;
    float s = 0.f, s2 = 0.f;
    for (int r = blockIdx.x * 2 + half; r < n; r += gridDim.x * 2) {
        size_t idx = (size_t)r * D_ + c;
        float v = ADD ? (a[idx] + b[idx]) : a[idx];
        if (ADD) y[idx] = v;
        s += v; s2 += v * v;
    }
    __shared__ float ls[256], ls2[256];
    ls[threadIdx.x] = s; ls2[threadIdx.x] = s2;
    __syncthreads();
    if (half == 0) {
        s  += ls[threadIdx.x + 128];
        s2 += ls2[threadIdx.x + 128];
        atomicAdd(sums + c, s);
        atomicAdd(sums + 128 + c, s2);
    }
}

__global__ void bn_norm_kernel(const float* __restrict__ x,
                               const float* __restrict__ stats,
                               const float* __restrict__ g, const float* __restrict__ b,
                               float* __restrict__ out, int n, int total)
{
    int i = blockIdx.x * blockDim.x + threadIdx.x;
    if (i >= total) return;
    int c = i & 127;
    float invn = 1.f / (float)n;
    float m   = stats[c] * invn;
    float var = stats[128 + c] * invn - m * m;
    float rs  = rsqrtf(var + 1e-5f);
    out[i] = (x[i] - m) * rs * g[c] + b[c];
}

// ---------------------------------------------------------------------------
extern "C" void kernel_launch(void* const* d_in, const int* in_sizes, int n_in,
                              void* d_out, int out_size, void* d_ws, size_t ws_size,
                              hipStream_t stream)
{
    const float* h    = (const float*)d_in[0];
    const int*   src  = (const int*)d_in[1];
    const int*   dst  = (const int*)d_in[2];
    const float* Win  = (const float*)d_in[3];
    const float* bin_ = (const float*)d_in[4];
    const float* Wout = (const float*)d_in[5];
    const float* bout = (const float*)d_in[6];
    const float* Wte1 = (const float*)d_in[7];
    const float* bte1 = (const float*)d_in[8];
    const float* Wte2 = (const float*)d_in[9];
    const float* bte2 = (const float*)d_in[10];
    const float* ln1g = (const float*)d_in[11];
    const float* ln1b = (const float*)d_in[12];
    const float* ln2g = (const float*)d_in[13];
    const float* ln2b = (const float*)d_in[14];
    const float* WQ   = (const float*)d_in[15];
    const float* WK   = (const float*)d_in[16];
    const float* WV   = (const float*)d_in[17];
    const float* W1   = (const float*)d_in[18];
    const float* b1   = (const float*)d_in[19];
    const float* W2   = (const float*)d_in[20];
    const float* b2   = (const float*)d_in[21];
    const float* bn1g = (const float*)d_in[22];
    const float* bn1b = (const float*)d_in[23];
    const float* bn2g = (const float*)d_in[24];
    const float* bn2b = (const float*)d_in[25];

    const int N_ = in_sizes[0] / D_;
    const int E_ = in_sizes[1];
    const size_t S = (size_t)N_ * D_;

    float* ws = (float*)d_ws;
    size_t need = (6 * S + 512) * sizeof(float) + (size_t)(N_ + E_ + 256) * sizeof(int);
    if (ws_size < need) return;
    float* bufA  = ws;            // S
    float* bufB  = ws + S;        // S
    float* bufC  = ws + 2 * S;    // 4S
    float* stats = ws + 6 * S;    // 512
    int* rowptr  = (int*)(ws + 6 * S + 512);  // N
    int* csr_src = rowptr + N_;               // E
    int* bsum    = csr_src + E_;              // 256

    dim3 blk(256);
    const int rowChunks = (N_ + 31) / 32;
    const int totElems  = N_ * D_;
    const dim3 gElem((totElems + 255) / 256);
    const dim3 gRow((N_ + 3) / 4);
    const int nb = (N_ + 255) / 256;   // scan blocks (<=256 assumed: N<=65536)

    hipMemsetAsync(stats, 0, 512 * sizeof(float), stream);
    hipMemsetAsync(rowptr, 0, (size_t)N_ * sizeof(int), stream);

    // --- CSR build (independent of feature pipeline) ---
    hist_kernel<<<dim3((E_ + 255) / 256), blk, 0, stream>>>(dst, rowptr, E_);
    scan_block_kernel<<<dim3(nb), blk, 0, stream>>>(rowptr, bsum, N_);
    scan_bsum_kernel<<<dim3(1), blk, 0, stream>>>(bsum, nb);
    add_off_kernel<<<dim3(nb), blk, 0, stream>>>(rowptr, bsum, N_);
    scatter_kernel<<<dim3((E_ + 255) / 256), blk, 0, stream>>>(src, dst, rowptr, csr_src, E_);

    // --- per-node TransformerEncoder (seq_len==1 => attn_out = out_proj(V)) ---
    gemm_kernel<false><<<dim3(rowChunks, 1), blk, 0, stream>>>(
        h, Win + 256 * 128, bin_ + 256, bufA, N_, 128, 128);          // v
    gemm_kernel<false><<<dim3(rowChunks, 1), blk, 0, stream>>>(
        bufA, Wout, bout, bufB, N_, 128, 128);                        // out_proj(v)
    ln_residual_kernel<<<gRow, blk, 0, stream>>>(h, bufB, ln1g, ln1b, bufB, N_);  // x
    gemm_kernel<true><<<dim3(rowChunks, 4), blk, 0, stream>>>(
        bufB, Wte1, bte1, bufC, N_, 128, 512);                        // ff1
    gemm_kernel<false><<<dim3(rowChunks, 1), blk, 0, stream>>>(
        bufC, Wte2, bte2, bufA, N_, 512, 128);                        // ff
    float* hsub = bufC;
    ln_residual_kernel<<<gRow, blk, 0, stream>>>(bufB, bufA, ln2g, ln2b, hsub, N_);

    // --- graph multi-head attention (gather form) ---
    gemm_kernel<false><<<dim3(rowChunks, 1), blk, 0, stream>>>(
        hsub, WQ, nullptr, bufA, N_, 128, 128);                       // Q
    gemm_kernel<false><<<dim3(rowChunks, 1), blk, 0, stream>>>(
        hsub, WK, nullptr, bufB, N_, 128, 128);                       // K
    float* Vbuf = bufC + S;
    gemm_kernel<false><<<dim3(rowChunks, 1), blk, 0, stream>>>(
        hsub, WV, nullptr, Vbuf, N_, 128, 128);                       // V
    float* y1 = bufC + 2 * S;
    attn_agg_kernel<<<gRow, blk, 0, stream>>>(
        rowptr, csr_src, bufA, bufB, Vbuf, hsub, y1, N_);

    // --- BN1 ---
    bn_stats_kernel<false><<<dim3(256), blk, 0, stream>>>(y1, nullptr, nullptr, stats, N_);
    bn_norm_kernel<<<gElem, blk, 0, stream>>>(y1, stats, bn1g, bn1b, bufB, N_, totElems); // hh

    // --- FFN + BN2 ---
    gemm_kernel<true><<<dim3(rowChunks, 2), blk, 0, stream>>>(
        bufB, W1, b1, bufC, N_, 128, 256);                            // f1 (hsub dead)
    gemm_kernel<false><<<dim3(rowChunks, 1), blk, 0, stream>>>(
        bufC, W2, b2, bufA, N_, 256, 128);                            // f2
    // y2 = hh + f2 (fused into stats pass), then BN2 -> d_out
    float* y2 = bufC + 2 * S;
    bn_stats_kernel<true><<<dim3(256), blk, 0, stream>>>(bufB, bufA, y2, stats + 256, N_);
    bn_norm_kernel<<<gElem, blk, 0, stream>>>(y2, stats + 256, bn2g, bn2b,
                                              (float*)d_out, N_, totElems);
}

// Round 3
// 381.719 us; speedup vs baseline: 3.0832x; 2.2202x over previous
//
#include <hip/hip_runtime.h>
#include <hip/hip_bf16.h>

// GraphTransformerLayer on MI355X — round 3: bf16 MFMA GEMMs + bf16 activations.
// N=50000 nodes, E=500000 edges, D=128, H=8, DH=16.

#define D_ 128

typedef __attribute__((ext_vector_type(8))) short short8;
typedef __attribute__((ext_vector_type(4))) short short4v;
typedef __attribute__((ext_vector_type(4))) float f32x4;

__device__ __forceinline__ float b2f(ushort u) {
    union { uint u32; float f; } x; x.u32 = ((uint)u) << 16; return x.f;
}
__device__ __forceinline__ ushort f2b(float f) {
    union { __hip_bfloat16 h; ushort u; } v; v.h = __float2bfloat16(f); return v.u;
}

// ---------------------------------------------------------------------------
// bf16 MFMA GEMM: C[n x M] = A[n x K] @ W[M x K]^T (+bias) (+relu)
// 256 threads = 4 waves; tile 128x128; wave computes 64x64 (4x4 frags 16x16).
// BK=32 staged in LDS with 16B-chunk XOR swizzle (2-way conflicts = free).
// MFMA operand swap: mfma(Wfrag, Afrag) -> lane holds C[row][4 consecutive cols].
// ---------------------------------------------------------------------------
template<bool RELU, bool F32OUT>
__global__ __launch_bounds__(256) void gemm_bf16(
    const ushort* __restrict__ A, const ushort* __restrict__ W,
    const float* __restrict__ bias, void* __restrict__ C,
    int n, int K, int M)
{
    __shared__ ushort Abuf[128 * 32];
    __shared__ ushort Bbuf[128 * 32];
    const int t    = threadIdx.x;
    const int lane = t & 63;
    const int w    = t >> 6;
    const int r0   = blockIdx.x * 128;
    const int c0   = blockIdx.y * 128;
    const int wr   = (w >> 1) * 64;
    const int wc   = (w & 1) * 64;
    const int rl   = lane & 15;
    const int kh   = lane >> 4;          // 16B k-chunk index 0..3

    f32x4 acc[4][4] = {};                // [m][nn]

    for (int kc = 0; kc < K; kc += 32) {
        short8 aval[2], bval[2];
        #pragma unroll
        for (int rep = 0; rep < 2; ++rep) {
            int i   = t + rep * 256;     // [0,512)
            int row = i >> 2, ch = i & 3;
            int gr  = r0 + row;
            short8 v = {};
            if (gr < n)
                v = *reinterpret_cast<const short8*>(A + (size_t)gr * K + kc + ch * 8);
            aval[rep] = v;
            bval[rep] = *reinterpret_cast<const short8*>(W + (size_t)(c0 + row) * K + kc + ch * 8);
        }
        __syncthreads();   // previous iteration's LDS reads complete
        #pragma unroll
        for (int rep = 0; rep < 2; ++rep) {
            int i   = t + rep * 256;
            int row = i >> 2, ch = i & 3;
            int sw  = ch ^ ((row >> 1) & 3);
            *reinterpret_cast<short8*>(&Abuf[row * 32 + sw * 8]) = aval[rep];
            *reinterpret_cast<short8*>(&Bbuf[row * 32 + sw * 8]) = bval[rep];
        }
        __syncthreads();
        short8 af[4], bfr[4];
        #pragma unroll
        for (int m = 0; m < 4; ++m) {
            int row = wr + m * 16 + rl;
            af[m] = *reinterpret_cast<const short8*>(&Abuf[row * 32 + (kh ^ ((row >> 1) & 3)) * 8]);
        }
        #pragma unroll
        for (int nn = 0; nn < 4; ++nn) {
            int col = wc + nn * 16 + rl;
            bfr[nn] = *reinterpret_cast<const short8*>(&Bbuf[col * 32 + (kh ^ ((col >> 1) & 3)) * 8]);
        }
        #pragma unroll
        for (int m = 0; m < 4; ++m)
            #pragma unroll
            for (int nn = 0; nn < 4; ++nn)
                acc[m][nn] = __builtin_amdgcn_mfma_f32_16x16x32_bf16(
                    bfr[nn], af[m], acc[m][nn], 0, 0, 0);
    }

    const int ch4 = kh * 4;
    #pragma unroll
    for (int m = 0; m < 4; ++m) {
        int r = r0 + wr + m * 16 + rl;
        if (r >= n) continue;
        #pragma unroll
        for (int nn = 0; nn < 4; ++nn) {
            int c = c0 + wc + nn * 16 + ch4;
            f32x4 v = acc[m][nn];
            float4 bb = make_float4(0.f, 0.f, 0.f, 0.f);
            if (bias) bb = *reinterpret_cast<const float4*>(bias + c);
            float o0 = v[0] + bb.x, o1 = v[1] + bb.y, o2 = v[2] + bb.z, o3 = v[3] + bb.w;
            if (RELU) {
                o0 = fmaxf(o0, 0.f); o1 = fmaxf(o1, 0.f);
                o2 = fmaxf(o2, 0.f); o3 = fmaxf(o3, 0.f);
            }
            if (F32OUT) {
                float4 o4 = make_float4(o0, o1, o2, o3);
                *reinterpret_cast<float4*>((float*)C + (size_t)r * M + c) = o4;
            } else {
                short4v p;
                p[0] = (short)f2b(o0); p[1] = (short)f2b(o1);
                p[2] = (short)f2b(o2); p[3] = (short)f2b(o3);
                *reinterpret_cast<short4v*>((ushort*)C + (size_t)r * M + c) = p;
            }
        }
    }
}

// ---------------------------------------------------------------------------
// out_bf16 = LayerNorm(a + b) over D=128. One wave per row, 2 ch/lane.
// ---------------------------------------------------------------------------
template<bool A_F32>
__global__ __launch_bounds__(256) void ln_residual_kernel(
    const void* __restrict__ a, const ushort* __restrict__ b,
    const float* __restrict__ g, const float* __restrict__ be,
    ushort* __restrict__ out, int n)
{
    int wid  = (blockIdx.x * blockDim.x + threadIdx.x) >> 6;
    int lane = threadIdx.x & 63;
    if (wid >= n) return;
    float a0, a1;
    if (A_F32) {
        float2 av = reinterpret_cast<const float2*>((const float*)a + (size_t)wid * D_)[lane];
        a0 = av.x; a1 = av.y;
    } else {
        ushort2 av = reinterpret_cast<const ushort2*>((const ushort*)a + (size_t)wid * D_)[lane];
        a0 = b2f(av.x); a1 = b2f(av.y);
    }
    ushort2 bv = reinterpret_cast<const ushort2*>(b + (size_t)wid * D_)[lane];
    float x0 = a0 + b2f(bv.x), x1 = a1 + b2f(bv.y);
    float s  = x0 + x1;
    float s2 = x0 * x0 + x1 * x1;
    #pragma unroll
    for (int o = 1; o < 64; o <<= 1) {
        s  += __shfl_xor(s,  o);
        s2 += __shfl_xor(s2, o);
    }
    float m   = s * (1.f / 128.f);
    float var = s2 * (1.f / 128.f) - m * m;
    float rs  = rsqrtf(var + 1e-5f);
    float2 gv  = reinterpret_cast<const float2*>(g)[lane];
    float2 bev = reinterpret_cast<const float2*>(be)[lane];
    ushort2 o2;
    o2.x = f2b((x0 - m) * rs * gv.x + bev.x);
    o2.y = f2b((x1 - m) * rs * gv.y + bev.y);
    reinterpret_cast<ushort2*>(out + (size_t)wid * D_)[lane] = o2;
}

// ---------------------------------------------------------------------------
// CSR build
// ---------------------------------------------------------------------------
__global__ void hist_kernel(const int* __restrict__ dst, int* __restrict__ cnt, int E_)
{
    int e = blockIdx.x * blockDim.x + threadIdx.x;
    if (e < E_) atomicAdd(cnt + dst[e], 1);
}

__global__ __launch_bounds__(256) void scan_block_kernel(
    int* __restrict__ data, int* __restrict__ bsum, int n)
{
    __shared__ int tmp[256];
    int i = blockIdx.x * 256 + threadIdx.x;
    int v = (i < n) ? data[i] : 0;
    tmp[threadIdx.x] = v;
    __syncthreads();
    #pragma unroll
    for (int o = 1; o < 256; o <<= 1) {
        int y = (threadIdx.x >= o) ? tmp[threadIdx.x - o] : 0;
        __syncthreads();
        tmp[threadIdx.x] += y;
        __syncthreads();
    }
    if (i < n) data[i] = tmp[threadIdx.x] - v;
    if (threadIdx.x == 255) bsum[blockIdx.x] = tmp[255];
}

__global__ __launch_bounds__(256) void scan_bsum_kernel(int* __restrict__ bsum, int nb)
{
    __shared__ int tmp[256];
    int v = (threadIdx.x < nb) ? bsum[threadIdx.x] : 0;
    tmp[threadIdx.x] = v;
    __syncthreads();
    #pragma unroll
    for (int o = 1; o < 256; o <<= 1) {
        int y = (threadIdx.x >= o) ? tmp[threadIdx.x - o] : 0;
        __syncthreads();
        tmp[threadIdx.x] += y;
        __syncthreads();
    }
    if (threadIdx.x < nb) bsum[threadIdx.x] = tmp[threadIdx.x] - v;
}

__global__ void add_off_kernel(int* __restrict__ data, const int* __restrict__ bsum, int n)
{
    int i = blockIdx.x * blockDim.x + threadIdx.x;
    if (i < n) data[i] += bsum[i >> 8];
}

__global__ void scatter_kernel(const int* __restrict__ src, const int* __restrict__ dst,
                               int* __restrict__ rowptr, int* __restrict__ csr_src, int E_)
{
    int e = blockIdx.x * blockDim.x + threadIdx.x;
    if (e >= E_) return;
    int pos = atomicAdd(rowptr + dst[e], 1);
    csr_src[pos] = src[e];
}

// ---------------------------------------------------------------------------
// Gather attention aggregation (bf16 inputs). Writes y1 = hsub + wV/z (f32).
// ---------------------------------------------------------------------------
__global__ __launch_bounds__(256) void attn_agg_kernel(
    const int* __restrict__ rowptr, const int* __restrict__ csr_src,
    const ushort* __restrict__ Q, const ushort* __restrict__ K,
    const ushort* __restrict__ V, const ushort* __restrict__ hsub,
    float* __restrict__ out, int n)
{
    int node = (blockIdx.x * blockDim.x + threadIdx.x) >> 6;
    if (node >= n) return;
    int lane = threadIdx.x & 63;
    int start = node ? rowptr[node - 1] : 0;
    int end   = rowptr[node];
    ushort2 qu = reinterpret_cast<const ushort2*>(Q + (size_t)node * D_)[lane];
    float qx = b2f(qu.x), qy = b2f(qu.y);
    float ax = 0.f, ay = 0.f, zh = 0.f;
    for (int j = start; j < end; ++j) {
        int s = csr_src[j];
        ushort2 ku = reinterpret_cast<const ushort2*>(K + (size_t)s * D_)[lane];
        float p = b2f(ku.x) * qx + b2f(ku.y) * qy;
        p += __shfl_xor(p, 1);
        p += __shfl_xor(p, 2);
        p += __shfl_xor(p, 4);
        float sc = __expf(fminf(fmaxf(p * 0.25f, -5.f), 5.f));
        ushort2 vu = reinterpret_cast<const ushort2*>(V + (size_t)s * D_)[lane];
        ax = fmaf(sc, b2f(vu.x), ax);
        ay = fmaf(sc, b2f(vu.y), ay);
        zh += sc;
    }
    ushort2 hv = reinterpret_cast<const ushort2*>(hsub + (size_t)node * D_)[lane];
    float inv = 1.f / zh;
    float2 o2;
    o2.x = b2f(hv.x) + ax * inv;
    o2.y = b2f(hv.y) + ay * inv;
    reinterpret_cast<float2*>(out + (size_t)node * D_)[lane] = o2;
}

// ---------------------------------------------------------------------------
// BN stats over f32 input
// ---------------------------------------------------------------------------
__global__ __launch_bounds__(256) void bn_stats_kernel(
    const float* __restrict__ x, float* __restrict__ sums, int n)
{
    int c    = threadIdx.x & 127;
    int half = threadIdx.x >> 7;
    float s = 0.f, s2 = 0.f;
    for (int r = blockIdx.x * 2 + half; r < n; r += gridDim.x * 2) {
        float v = x[(size_t)r * D_ + c];
        s += v; s2 += v * v;
    }
    __shared__ float ls[256], ls2[256];
    ls[threadIdx.x] = s; ls2[threadIdx.x] = s2;
    __syncthreads();
    if (half == 0) {
        s  += ls[threadIdx.x + 128];
        s2 += ls2[threadIdx.x + 128];
        atomicAdd(sums + c, s);
        atomicAdd(sums + 128 + c, s2);
    }
}

// y = bf16(a) + f32(b), stats over y, y stored f32
__global__ __launch_bounds__(256) void bn_stats_add_kernel(
    const ushort* __restrict__ a, const float* __restrict__ b,
    float* __restrict__ y, float* __restrict__ sums, int n)
{
    int c    = threadIdx.x & 127;
    int half = threadIdx.x >> 7;
    float s = 0.f, s2 = 0.f;
    for (int r = blockIdx.x * 2 + half; r < n; r += gridDim.x * 2) {
        size_t idx = (size_t)r * D_ + c;
        float v = b2f(a[idx]) + b[idx];
        y[idx] = v;
        s += v; s2 += v * v;
    }
    __shared__ float ls[256], ls2[256];
    ls[threadIdx.x] = s; ls2[threadIdx.x] = s2;
    __syncthreads();
    if (half == 0) {
        s  += ls[threadIdx.x + 128];
        s2 += ls2[threadIdx.x + 128];
        atomicAdd(sums + c, s);
        atomicAdd(sums + 128 + c, s2);
    }
}

template<bool F32OUT>
__global__ void bn_norm_kernel(const float* __restrict__ x,
                               const float* __restrict__ stats,
                               const float* __restrict__ g, const float* __restrict__ b,
                               void* __restrict__ out, int n, int total)
{
    int i = blockIdx.x * blockDim.x + threadIdx.x;
    if (i >= total) return;
    int c = i & 127;
    float invn = 1.f / (float)n;
    float m   = stats[c] * invn;
    float var = stats[128 + c] * invn - m * m;
    float rs  = rsqrtf(var + 1e-5f);
    float v = (x[i] - m) * rs * g[c] + b[c];
    if (F32OUT) ((float*)out)[i] = v;
    else        ((ushort*)out)[i] = f2b(v);
}

// ---------------------------------------------------------------------------
// f32 -> bf16 converters
// ---------------------------------------------------------------------------
__global__ void cvt_kernel(const float* __restrict__ in, ushort* __restrict__ out, int n4)
{
    int i = blockIdx.x * blockDim.x + threadIdx.x;
    if (i >= n4) return;
    float4 v = reinterpret_cast<const float4*>(in)[i];
    short4v p;
    p[0] = (short)f2b(v.x); p[1] = (short)f2b(v.y);
    p[2] = (short)f2b(v.z); p[3] = (short)f2b(v.w);
    reinterpret_cast<short4v*>(out)[i] = p;
}

struct WPtrs { const float* p[9]; };

__global__ __launch_bounds__(256) void cvt_w_kernel(WPtrs wp, ushort* __restrict__ out)
{
    const int off[10] = {0, 16384, 32768, 98304, 163840, 180224, 196608, 212992, 245760, 278528};
    int i = blockIdx.x * 256 + threadIdx.x;
    if (i >= 278528) return;
    int s = 0;
    #pragma unroll
    for (int j = 1; j < 9; ++j) if (i >= off[j]) s = j;
    out[i] = f2b(wp.p[s][i - off[s]]);
}

// ---------------------------------------------------------------------------
extern "C" void kernel_launch(void* const* d_in, const int* in_sizes, int n_in,
                              void* d_out, int out_size, void* d_ws, size_t ws_size,
                              hipStream_t stream)
{
    const float* h    = (const float*)d_in[0];
    const int*   src  = (const int*)d_in[1];
    const int*   dst  = (const int*)d_in[2];
    const float* Win  = (const float*)d_in[3];
    const float* bin_ = (const float*)d_in[4];
    const float* Wout = (const float*)d_in[5];
    const float* bout = (const float*)d_in[6];
    const float* Wte1 = (const float*)d_in[7];
    const float* bte1 = (const float*)d_in[8];
    const float* Wte2 = (const float*)d_in[9];
    const float* bte2 = (const float*)d_in[10];
    const float* ln1g = (const float*)d_in[11];
    const float* ln1b = (const float*)d_in[12];
    const float* ln2g = (const float*)d_in[13];
    const float* ln2b = (const float*)d_in[14];
    const float* WQ   = (const float*)d_in[15];
    const float* WK   = (const float*)d_in[16];
    const float* WV   = (const float*)d_in[17];
    const float* W1   = (const float*)d_in[18];
    const float* b1   = (const float*)d_in[19];
    const float* W2   = (const float*)d_in[20];
    const float* b2   = (const float*)d_in[21];
    const float* bn1g = (const float*)d_in[22];
    const float* bn1b = (const float*)d_in[23];
    const float* bn2g = (const float*)d_in[24];
    const float* bn2b = (const float*)d_in[25];

    const int N_ = in_sizes[0] / D_;
    const int E_ = in_sizes[1];
    const size_t S  = (size_t)N_ * D_;   // f32 elems of one N x 128 buffer
    const size_t S2 = S / 2;             // float-units of one N x 128 bf16 buffer

    float* ws = (float*)d_ws;
    // layout (float units): A,B,C bf16 NxD (S2 each); D bf16 Nx512 (4*S2);
    // E f32 NxD (2*S2); F f32 NxD (2*S2); weights bf16; stats; ints.
    size_t off_W     = 11 * S2;
    size_t off_stats = off_W + 139264;
    size_t need = (off_stats + 512) * sizeof(float) + (size_t)(N_ + E_ + 256) * sizeof(int)
                + 262144;  // OOB slack
    if (ws_size < need) return;

    ushort* bufA = (ushort*)ws;                  // bf16 NxD
    ushort* bufB = (ushort*)(ws + S2);
    ushort* bufC = (ushort*)(ws + 2 * S2);
    ushort* bufD = (ushort*)(ws + 3 * S2);       // bf16 Nx512
    float*  bufE = ws + 7 * S2;                  // f32 NxD
    float*  bufF = ws + 9 * S2;                  // f32 NxD
    ushort* wbf  = (ushort*)(ws + off_W);
    float*  stats = ws + off_stats;
    int* rowptr  = (int*)(ws + off_stats + 512);
    int* csr_src = rowptr + N_;
    int* bsum    = csr_src + E_;

    const ushort* WinV_bf = wbf;
    const ushort* Wout_bf = wbf + 16384;
    const ushort* Wte1_bf = wbf + 32768;
    const ushort* Wte2_bf = wbf + 98304;
    const ushort* WQ_bf   = wbf + 163840;
    const ushort* WK_bf   = wbf + 180224;
    const ushort* WV_bf   = wbf + 196608;
    const ushort* W1_bf   = wbf + 212992;
    const ushort* W2_bf   = wbf + 245760;

    dim3 blk(256);
    const int rowBlocks = (N_ + 127) / 128;
    const int totElems  = N_ * D_;
    const dim3 gElem((totElems + 255) / 256);
    const dim3 gRow((N_ + 3) / 4);
    const int nb = (N_ + 255) / 256;

    hipMemsetAsync(stats, 0, 512 * sizeof(float), stream);
    hipMemsetAsync(rowptr, 0, (size_t)N_ * sizeof(int), stream);

    // --- CSR build ---
    hist_kernel<<<dim3((E_ + 255) / 256), blk, 0, stream>>>(dst, rowptr, E_);
    scan_block_kernel<<<dim3(nb), blk, 0, stream>>>(rowptr, bsum, N_);
    scan_bsum_kernel<<<dim3(1), blk, 0, stream>>>(bsum, nb);
    add_off_kernel<<<dim3(nb), blk, 0, stream>>>(rowptr, bsum, N_);
    scatter_kernel<<<dim3((E_ + 255) / 256), blk, 0, stream>>>(src, dst, rowptr, csr_src, E_);

    // --- converters ---
    cvt_kernel<<<dim3((totElems / 4 + 255) / 256), blk, 0, stream>>>(h, bufA, totElems / 4);
    WPtrs wp;
    wp.p[0] = Win + 256 * 128; wp.p[1] = Wout; wp.p[2] = Wte1; wp.p[3] = Wte2;
    wp.p[4] = WQ; wp.p[5] = WK; wp.p[6] = WV; wp.p[7] = W1; wp.p[8] = W2;
    cvt_w_kernel<<<dim3((278528 + 255) / 256), blk, 0, stream>>>(wp, wbf);

    // --- per-node TransformerEncoder (seq_len==1 => attn_out = out_proj(V)) ---
    gemm_bf16<false, false><<<dim3(rowBlocks, 1), blk, 0, stream>>>(
        bufA, WinV_bf, bin_ + 256, bufB, N_, 128, 128);                  // v -> B
    gemm_bf16<false, false><<<dim3(rowBlocks, 1), blk, 0, stream>>>(
        bufB, Wout_bf, bout, bufC, N_, 128, 128);                        // t -> C
    ln_residual_kernel<true><<<gRow, blk, 0, stream>>>(h, bufC, ln1g, ln1b, bufA, N_);  // x -> A
    gemm_bf16<true, false><<<dim3(rowBlocks, 4), blk, 0, stream>>>(
        bufA, Wte1_bf, bte1, bufD, N_, 128, 512);                        // ff1 -> D
    gemm_bf16<false, false><<<dim3(rowBlocks, 1), blk, 0, stream>>>(
        bufD, Wte2_bf, bte2, bufB, N_, 512, 128);                        // ff -> B
    ln_residual_kernel<false><<<gRow, blk, 0, stream>>>(bufA, bufB, ln2g, ln2b, bufC, N_); // hsub -> C

    // --- graph multi-head attention (gather form) ---
    ushort* Qb = bufA;
    ushort* Kb = bufD;
    ushort* Vb = bufD + S;   // S ushorts = S2 floats offset
    gemm_bf16<false, false><<<dim3(rowBlocks, 1), blk, 0, stream>>>(
        bufC, WQ_bf, nullptr, Qb, N_, 128, 128);
    gemm_bf16<false, false><<<dim3(rowBlocks, 1), blk, 0, stream>>>(
        bufC, WK_bf, nullptr, Kb, N_, 128, 128);
    gemm_bf16<false, false><<<dim3(rowBlocks, 1), blk, 0, stream>>>(
        bufC, WV_bf, nullptr, Vb, N_, 128, 128);
    attn_agg_kernel<<<gRow, blk, 0, stream>>>(
        rowptr, csr_src, Qb, Kb, Vb, bufC, bufE, N_);                    // y1 -> E (f32)

    // --- BN1 ---
    bn_stats_kernel<<<dim3(512), blk, 0, stream>>>(bufE, stats, N_);
    bn_norm_kernel<false><<<gElem, blk, 0, stream>>>(bufE, stats, bn1g, bn1b, bufB, N_, totElems); // hh -> B (bf16)

    // --- FFN + BN2 ---
    gemm_bf16<true, false><<<dim3(rowBlocks, 2), blk, 0, stream>>>(
        bufB, W1_bf, b1, bufD, N_, 128, 256);                            // f1 -> D
    gemm_bf16<false, true><<<dim3(rowBlocks, 1), blk, 0, stream>>>(
        bufD, W2_bf, b2, bufF, N_, 256, 128);                            // f2 -> F (f32)
    bn_stats_add_kernel<<<dim3(512), blk, 0, stream>>>(bufB, bufF, bufE, stats + 256, N_); // y2 -> E
    bn_norm_kernel<true><<<gElem, blk, 0, stream>>>(bufE, stats + 256, bn2g, bn2b,
                                                    d_out, N_, totElems);
}

// Round 5
// 322.670 us; speedup vs baseline: 3.6475x; 1.1830x over previous
//
#include <hip/hip_runtime.h>
#include <hip/hip_bf16.h>

// GraphTransformerLayer on MI355X — round 5: round-4 design + fixed ws layout.
// N=50000 nodes, E=500000 edges, D=128, H=8, DH=16.

#define D_ 128

typedef __attribute__((ext_vector_type(8))) short short8;
typedef __attribute__((ext_vector_type(4))) short short4v;
typedef __attribute__((ext_vector_type(4))) float f32x4;

__device__ __forceinline__ float b2f(ushort u) {
    union { uint u32; float f; } x; x.u32 = ((uint)u) << 16; return x.f;
}
__device__ __forceinline__ ushort f2b(float f) {
    union { __hip_bfloat16 h; ushort u; } v; v.h = __float2bfloat16(f); return v.u;
}

// ---------------------------------------------------------------------------
// bf16 MFMA GEMM: C[n x M] = A[n x K] @ W[M x K]^T (+bias) (+relu)
// 256 threads = 4 waves; tile 128x128; wave computes 64x64 (4x4 frags 16x16).
// AMODE: 0 = A bf16; 1 = A f32 (convert in staging); 2 = A bf16 + BN1 norm
//        (x*s[c]+t[c], K must be 128).
// EPI:   0 = bf16 store; 2 = bf16 store of acc + bias + BN1(y1res) (M must be 128).
// ---------------------------------------------------------------------------
template<int AMODE, int EPI, bool RELU>
__global__ __launch_bounds__(256) void gemm_bf16(
    const void* __restrict__ Aptr, const ushort* __restrict__ W,
    const float* __restrict__ bias, void* __restrict__ C,
    const float* __restrict__ stats, const float* __restrict__ bng,
    const float* __restrict__ bnb, const ushort* __restrict__ y1res,
    float invn, int n, int K, int M)
{
    __shared__ ushort Abuf[128 * 32];
    __shared__ ushort Bbuf[128 * 32];
    __shared__ float s_sh[128], t_sh[128];

    const int t    = threadIdx.x;
    const int lane = t & 63;
    const int w    = t >> 6;
    const int r0   = blockIdx.x * 128;
    const int c0   = blockIdx.y * 128;
    const int wr   = (w >> 1) * 64;
    const int wc   = (w & 1) * 64;
    const int rl   = lane & 15;
    const int kh   = lane >> 4;

    if (AMODE == 2 || EPI == 2) {
        if (t < 128) {
            float m   = stats[t] * invn;
            float var = stats[128 + t] * invn - m * m;
            float rs  = rsqrtf(var + 1e-5f);
            float s   = rs * bng[t];
            s_sh[t] = s;
            t_sh[t] = bnb[t] - m * s;
        }
        __syncthreads();
    }

    f32x4 acc[4][4] = {};

    for (int kc = 0; kc < K; kc += 32) {
        short8 aval[2], bval[2];
        #pragma unroll
        for (int rep = 0; rep < 2; ++rep) {
            int i   = t + rep * 256;
            int row = i >> 2, ch = i & 3;
            int gr  = r0 + row;
            short8 v = {};
            if (AMODE == 1) {
                if (gr < n) {
                    const float* Af = (const float*)Aptr;
                    float4 f0 = *reinterpret_cast<const float4*>(Af + (size_t)gr * K + kc + ch * 8);
                    float4 f1 = *reinterpret_cast<const float4*>(Af + (size_t)gr * K + kc + ch * 8 + 4);
                    v[0] = (short)f2b(f0.x); v[1] = (short)f2b(f0.y);
                    v[2] = (short)f2b(f0.z); v[3] = (short)f2b(f0.w);
                    v[4] = (short)f2b(f1.x); v[5] = (short)f2b(f1.y);
                    v[6] = (short)f2b(f1.z); v[7] = (short)f2b(f1.w);
                }
            } else {
                const ushort* Ab = (const ushort*)Aptr;
                if (gr < n)
                    v = *reinterpret_cast<const short8*>(Ab + (size_t)gr * K + kc + ch * 8);
                if (AMODE == 2) {
                    #pragma unroll
                    for (int q = 0; q < 8; ++q) {
                        int cch = kc + ch * 8 + q;
                        v[q] = (short)f2b(fmaf(b2f((ushort)v[q]), s_sh[cch], t_sh[cch]));
                    }
                }
            }
            aval[rep] = v;
            bval[rep] = *reinterpret_cast<const short8*>(W + (size_t)(c0 + row) * K + kc + ch * 8);
        }
        __syncthreads();   // previous iteration's LDS reads complete
        #pragma unroll
        for (int rep = 0; rep < 2; ++rep) {
            int i   = t + rep * 256;
            int row = i >> 2, ch = i & 3;
            int sw  = ch ^ ((row >> 1) & 3);
            *reinterpret_cast<short8*>(&Abuf[row * 32 + sw * 8]) = aval[rep];
            *reinterpret_cast<short8*>(&Bbuf[row * 32 + sw * 8]) = bval[rep];
        }
        __syncthreads();
        short8 af[4], bfr[4];
        #pragma unroll
        for (int m = 0; m < 4; ++m) {
            int row = wr + m * 16 + rl;
            af[m] = *reinterpret_cast<const short8*>(&Abuf[row * 32 + (kh ^ ((row >> 1) & 3)) * 8]);
        }
        #pragma unroll
        for (int nn = 0; nn < 4; ++nn) {
            int col = wc + nn * 16 + rl;
            bfr[nn] = *reinterpret_cast<const short8*>(&Bbuf[col * 32 + (kh ^ ((col >> 1) & 3)) * 8]);
        }
        #pragma unroll
        for (int m = 0; m < 4; ++m)
            #pragma unroll
            for (int nn = 0; nn < 4; ++nn)
                acc[m][nn] = __builtin_amdgcn_mfma_f32_16x16x32_bf16(
                    bfr[nn], af[m], acc[m][nn], 0, 0, 0);
    }

    const int ch4 = kh * 4;
    #pragma unroll
    for (int m = 0; m < 4; ++m) {
        int r = r0 + wr + m * 16 + rl;
        if (r >= n) continue;
        #pragma unroll
        for (int nn = 0; nn < 4; ++nn) {
            int c = c0 + wc + nn * 16 + ch4;
            f32x4 vacc = acc[m][nn];
            float4 bb = make_float4(0.f, 0.f, 0.f, 0.f);
            if (bias) bb = *reinterpret_cast<const float4*>(bias + c);
            float o0 = vacc[0] + bb.x, o1 = vacc[1] + bb.y;
            float o2 = vacc[2] + bb.z, o3 = vacc[3] + bb.w;
            if (RELU) {
                o0 = fmaxf(o0, 0.f); o1 = fmaxf(o1, 0.f);
                o2 = fmaxf(o2, 0.f); o3 = fmaxf(o3, 0.f);
            }
            if (EPI == 2) {
                short4v yv = *reinterpret_cast<const short4v*>(y1res + (size_t)r * 128 + c);
                o0 += fmaf(b2f((ushort)yv[0]), s_sh[c + 0], t_sh[c + 0]);
                o1 += fmaf(b2f((ushort)yv[1]), s_sh[c + 1], t_sh[c + 1]);
                o2 += fmaf(b2f((ushort)yv[2]), s_sh[c + 2], t_sh[c + 2]);
                o3 += fmaf(b2f((ushort)yv[3]), s_sh[c + 3], t_sh[c + 3]);
            }
            short4v p;
            p[0] = (short)f2b(o0); p[1] = (short)f2b(o1);
            p[2] = (short)f2b(o2); p[3] = (short)f2b(o3);
            *reinterpret_cast<short4v*>((ushort*)C + (size_t)r * M + c) = p;
        }
    }
}

// ---------------------------------------------------------------------------
// out_bf16 = LayerNorm(a + b) over D=128. One wave per row, 2 ch/lane.
// ---------------------------------------------------------------------------
template<bool A_F32>
__global__ __launch_bounds__(256) void ln_residual_kernel(
    const void* __restrict__ a, const ushort* __restrict__ b,
    const float* __restrict__ g, const float* __restrict__ be,
    ushort* __restrict__ out, int n)
{
    int wid  = (blockIdx.x * blockDim.x + threadIdx.x) >> 6;
    int lane = threadIdx.x & 63;
    if (wid >= n) return;
    float a0, a1;
    if (A_F32) {
        float2 av = reinterpret_cast<const float2*>((const float*)a + (size_t)wid * D_)[lane];
        a0 = av.x; a1 = av.y;
    } else {
        ushort2 av = reinterpret_cast<const ushort2*>((const ushort*)a + (size_t)wid * D_)[lane];
        a0 = b2f(av.x); a1 = b2f(av.y);
    }
    ushort2 bv = reinterpret_cast<const ushort2*>(b + (size_t)wid * D_)[lane];
    float x0 = a0 + b2f(bv.x), x1 = a1 + b2f(bv.y);
    float s  = x0 + x1;
    float s2 = x0 * x0 + x1 * x1;
    #pragma unroll
    for (int o = 1; o < 64; o <<= 1) {
        s  += __shfl_xor(s,  o);
        s2 += __shfl_xor(s2, o);
    }
    float m   = s * (1.f / 128.f);
    float var = s2 * (1.f / 128.f) - m * m;
    float rs  = rsqrtf(var + 1e-5f);
    float2 gv  = reinterpret_cast<const float2*>(g)[lane];
    float2 bev = reinterpret_cast<const float2*>(be)[lane];
    ushort2 o2;
    o2.x = f2b((x0 - m) * rs * gv.x + bev.x);
    o2.y = f2b((x1 - m) * rs * gv.y + bev.y);
    reinterpret_cast<ushort2*>(out + (size_t)wid * D_)[lane] = o2;
}

// ---------------------------------------------------------------------------
// CSR build
// ---------------------------------------------------------------------------
__global__ void hist_kernel(const int* __restrict__ dst, int* __restrict__ cnt, int E_)
{
    int e = blockIdx.x * blockDim.x + threadIdx.x;
    if (e < E_) atomicAdd(cnt + dst[e], 1);
}

__global__ __launch_bounds__(256) void scan_block_kernel(
    int* __restrict__ data, int* __restrict__ bsum, int n)
{
    __shared__ int tmp[256];
    int i = blockIdx.x * 256 + threadIdx.x;
    int v = (i < n) ? data[i] : 0;
    tmp[threadIdx.x] = v;
    __syncthreads();
    #pragma unroll
    for (int o = 1; o < 256; o <<= 1) {
        int y = (threadIdx.x >= o) ? tmp[threadIdx.x - o] : 0;
        __syncthreads();
        tmp[threadIdx.x] += y;
        __syncthreads();
    }
    if (i < n) data[i] = tmp[threadIdx.x] - v;
    if (threadIdx.x == 255) bsum[blockIdx.x] = tmp[255];
}

__global__ __launch_bounds__(256) void scan_bsum_kernel(int* __restrict__ bsum, int nb)
{
    __shared__ int tmp[256];
    int v = (threadIdx.x < nb) ? bsum[threadIdx.x] : 0;
    tmp[threadIdx.x] = v;
    __syncthreads();
    #pragma unroll
    for (int o = 1; o < 256; o <<= 1) {
        int y = (threadIdx.x >= o) ? tmp[threadIdx.x - o] : 0;
        __syncthreads();
        tmp[threadIdx.x] += y;
        __syncthreads();
    }
    if (threadIdx.x < nb) bsum[threadIdx.x] = tmp[threadIdx.x] - v;
}

__global__ void add_off_kernel(int* __restrict__ data, const int* __restrict__ bsum, int n)
{
    int i = blockIdx.x * blockDim.x + threadIdx.x;
    if (i < n) data[i] += bsum[i >> 8];
}

__global__ void scatter_kernel(const int* __restrict__ src, const int* __restrict__ dst,
                               int* __restrict__ rowptr, int* __restrict__ csr_src, int E_)
{
    int e = blockIdx.x * blockDim.x + threadIdx.x;
    if (e >= E_) return;
    int pos = atomicAdd(rowptr + dst[e], 1);
    csr_src[pos] = src[e];
}

// ---------------------------------------------------------------------------
// Gather attention. One wave per node = 4 edge-slots x 16 lanes (8 ch/lane).
// QKV interleaved [N][384]: Q at +0, K at +128, V at +256.
// Writes y1 = hsub + wV/z (bf16).
// ---------------------------------------------------------------------------
__global__ __launch_bounds__(256) void attn_agg_kernel(
    const int* __restrict__ rowptr, const int* __restrict__ csr_src,
    const ushort* __restrict__ QKV, const ushort* __restrict__ hsub,
    ushort* __restrict__ out, int n)
{
    int node = (blockIdx.x * blockDim.x + threadIdx.x) >> 6;
    if (node >= n) return;
    int lane = threadIdx.x & 63;
    int g    = lane >> 4;       // edge slot
    int sub  = lane & 15;       // channel chunk: ch [8*sub, 8*sub+8), head = sub>>1
    int start = node ? rowptr[node - 1] : 0;
    int end   = rowptr[node];

    short8 q8 = *reinterpret_cast<const short8*>(QKV + (size_t)node * 384 + sub * 8);
    float q[8];
    #pragma unroll
    for (int i = 0; i < 8; ++i) q[i] = b2f((ushort)q8[i]);

    float acc[8] = {};
    float zh = 0.f;
    for (int j = start; j < end; j += 4) {
        int idx  = j + g;
        bool act = idx < end;
        int s = csr_src[act ? idx : start];
        const ushort* kvp = QKV + (size_t)s * 384;
        short8 k8 = *reinterpret_cast<const short8*>(kvp + 128 + sub * 8);
        float p = 0.f;
        #pragma unroll
        for (int i = 0; i < 8; ++i) p = fmaf(b2f((ushort)k8[i]), q[i], p);
        p += __shfl_xor(p, 1);   // pair lanes complete the 16-dim head dot
        float sc = act ? __expf(fminf(fmaxf(p * 0.25f, -5.f), 5.f)) : 0.f;
        short8 v8 = *reinterpret_cast<const short8*>(kvp + 256 + sub * 8);
        #pragma unroll
        for (int i = 0; i < 8; ++i) acc[i] = fmaf(sc, b2f((ushort)v8[i]), acc[i]);
        zh += sc;
    }
    #pragma unroll
    for (int i = 0; i < 8; ++i) {
        acc[i] += __shfl_xor(acc[i], 16);
        acc[i] += __shfl_xor(acc[i], 32);
    }
    zh += __shfl_xor(zh, 16);
    zh += __shfl_xor(zh, 32);

    if (g == 0) {
        short8 h8 = *reinterpret_cast<const short8*>(hsub + (size_t)node * D_ + sub * 8);
        float inv = 1.f / zh;
        short8 o;
        #pragma unroll
        for (int i = 0; i < 8; ++i)
            o[i] = (short)f2b(b2f((ushort)h8[i]) + acc[i] * inv);
        *reinterpret_cast<short8*>(out + (size_t)node * D_ + sub * 8) = o;
    }
}

// ---------------------------------------------------------------------------
// BN stats over bf16 input: sums[c], sums[128+c].
// ---------------------------------------------------------------------------
__global__ __launch_bounds__(256) void bn_stats_kernel(
    const ushort* __restrict__ x, float* __restrict__ sums, int n)
{
    int c    = threadIdx.x & 127;
    int half = threadIdx.x >> 7;
    float s = 0.f, s2 = 0.f;
    for (int r = blockIdx.x * 2 + half; r < n; r += gridDim.x * 2) {
        float v = b2f(x[(size_t)r * D_ + c]);
        s += v; s2 += v * v;
    }
    __shared__ float ls[256], ls2[256];
    ls[threadIdx.x] = s; ls2[threadIdx.x] = s2;
    __syncthreads();
    if (half == 0) {
        s  += ls[threadIdx.x + 128];
        s2 += ls2[threadIdx.x + 128];
        atomicAdd(sums + c, s);
        atomicAdd(sums + 128 + c, s2);
    }
}

// final BN: bf16 in -> f32 out, 4 elems/thread
__global__ void bn_norm_kernel(const ushort* __restrict__ x,
                               const float* __restrict__ stats,
                               const float* __restrict__ g, const float* __restrict__ b,
                               float* __restrict__ out, float invn, int total4)
{
    int i = blockIdx.x * blockDim.x + threadIdx.x;
    if (i >= total4) return;
    int cb = (i << 2) & 127;
    short4v v = reinterpret_cast<const short4v*>(x)[i];
    float4 o;
    float r[4];
    #pragma unroll
    for (int q = 0; q < 4; ++q) {
        int c = cb + q;
        float m   = stats[c] * invn;
        float var = stats[128 + c] * invn - m * m;
        float rs  = rsqrtf(var + 1e-5f);
        r[q] = (b2f((ushort)v[q]) - m) * rs * g[c] + b[c];
    }
    o.x = r[0]; o.y = r[1]; o.z = r[2]; o.w = r[3];
    reinterpret_cast<float4*>(out)[i] = o;
}

// ---------------------------------------------------------------------------
// Weight prep: Wf = bf16(Wout @ WinV), bfused = Wout @ binV + bout.
// ---------------------------------------------------------------------------
__global__ __launch_bounds__(256) void fuse_w_kernel(
    const float* __restrict__ Win, const float* __restrict__ bin_,
    const float* __restrict__ Wout, const float* __restrict__ bout,
    ushort* __restrict__ Wf, float* __restrict__ bf)
{
    int idx = blockIdx.x * 256 + threadIdx.x;   // 16384 total
    int i = idx >> 7, c = idx & 127;
    const float* WinV = Win + 256 * 128;
    float s = 0.f;
    for (int j = 0; j < 128; ++j)
        s = fmaf(Wout[i * 128 + j], WinV[j * 128 + c], s);
    Wf[idx] = f2b(s);
    if (c == 0) {
        float tb = bout[i];
        for (int j = 0; j < 128; ++j)
            tb = fmaf(Wout[i * 128 + j], bin_[256 + j], tb);
        bf[i] = tb;
    }
}

// bf16 conversion of the 7 remaining weight mats (245760 elems, 4/thread)
struct WPtrs { const float* p[7]; };

__global__ __launch_bounds__(256) void cvt_w_kernel(WPtrs wp, ushort* __restrict__ out)
{
    const int off[8] = {0, 65536, 131072, 147456, 163840, 180224, 212992, 245760};
    int e0 = (blockIdx.x * 256 + threadIdx.x) * 4;
    if (e0 >= 245760) return;
    int s = 0;
    #pragma unroll
    for (int j = 1; j < 7; ++j) if (e0 >= off[j]) s = j;
    float4 f = *reinterpret_cast<const float4*>(wp.p[s] + (e0 - off[s]));
    short4v o;
    o[0] = (short)f2b(f.x); o[1] = (short)f2b(f.y);
    o[2] = (short)f2b(f.z); o[3] = (short)f2b(f.w);
    *reinterpret_cast<short4v*>(out + e0) = o;
}

// ---------------------------------------------------------------------------
extern "C" void kernel_launch(void* const* d_in, const int* in_sizes, int n_in,
                              void* d_out, int out_size, void* d_ws, size_t ws_size,
                              hipStream_t stream)
{
    const float* h    = (const float*)d_in[0];
    const int*   src  = (const int*)d_in[1];
    const int*   dst  = (const int*)d_in[2];
    const float* Win  = (const float*)d_in[3];
    const float* bin_ = (const float*)d_in[4];
    const float* Wout = (const float*)d_in[5];
    const float* bout = (const float*)d_in[6];
    const float* Wte1 = (const float*)d_in[7];
    const float* bte1 = (const float*)d_in[8];
    const float* Wte2 = (const float*)d_in[9];
    const float* bte2 = (const float*)d_in[10];
    const float* ln1g = (const float*)d_in[11];
    const float* ln1b = (const float*)d_in[12];
    const float* ln2g = (const float*)d_in[13];
    const float* ln2b = (const float*)d_in[14];
    const float* WQ   = (const float*)d_in[15];
    const float* WK   = (const float*)d_in[16];
    const float* WV   = (const float*)d_in[17];
    const float* W1   = (const float*)d_in[18];
    const float* b1   = (const float*)d_in[19];
    const float* W2   = (const float*)d_in[20];
    const float* b2   = (const float*)d_in[21];
    const float* bn1g = (const float*)d_in[22];
    const float* bn1b = (const float*)d_in[23];
    const float* bn2g = (const float*)d_in[24];
    const float* bn2b = (const float*)d_in[25];

    const int N_ = in_sizes[0] / D_;
    const int E_ = in_sizes[1];
    const size_t S2 = (size_t)N_ * D_ / 2;   // float-units of one N x 128 bf16 buffer

    float* ws = (float*)d_ws;
    // layout (float units):
    //   [0, S2)        bufA  (bf16 NxD)
    //   [S2, 2S2)      bufB  (bf16 NxD)
    //   [2S2, 3S2)     bufC  (bf16 NxD)
    //   [3S2, 7S2)     bufD  (bf16 Nx512 max: ff1/QKV/f1)
    //   [7S2, ...)     wbf (131072 f), bfused (128), stats (512), ints
    size_t off_tail = 7 * S2;
    size_t need = (off_tail + 131072 + 128 + 512) * sizeof(float)
                + (size_t)(N_ + E_ + 256) * sizeof(int) + 4096;
    if (ws_size < need) return;

    ushort* bufA   = (ushort*)ws;
    ushort* bufB   = (ushort*)(ws + S2);
    ushort* bufC   = (ushort*)(ws + 2 * S2);
    ushort* bufD   = (ushort*)(ws + 3 * S2);
    ushort* wbf    = (ushort*)(ws + off_tail);        // 262144 bf16 = 131072 f
    float*  bfused = ws + off_tail + 131072;          // 128
    float*  stats  = bfused + 128;                    // 512
    int* rowptr  = (int*)(stats + 512);               // N
    int* csr_src = rowptr + N_;                       // E
    int* bsum    = csr_src + E_;                      // 256

    const ushort* Wte1_bf = wbf;
    const ushort* Wte2_bf = wbf + 65536;
    const ushort* WQKV_bf = wbf + 131072;             // [WQ;WK;WV] 384x128
    const ushort* W1_bf   = wbf + 180224;
    const ushort* W2_bf   = wbf + 212992;
    ushort*       Wf_bf   = wbf + 245760;             // fused Wout@WinV

    dim3 blk(256);
    const int rowBlocks = (N_ + 127) / 128;
    const int totElems  = N_ * D_;
    const dim3 gRow((N_ + 3) / 4);
    const int nb = (N_ + 255) / 256;
    const float invn = 1.f / (float)N_;

    hipMemsetAsync(stats, 0, 512 * sizeof(float), stream);
    hipMemsetAsync(rowptr, 0, (size_t)N_ * sizeof(int), stream);

    // --- CSR build ---
    hist_kernel<<<dim3((E_ + 255) / 256), blk, 0, stream>>>(dst, rowptr, E_);
    scan_block_kernel<<<dim3(nb), blk, 0, stream>>>(rowptr, bsum, N_);
    scan_bsum_kernel<<<dim3(1), blk, 0, stream>>>(bsum, nb);
    add_off_kernel<<<dim3(nb), blk, 0, stream>>>(rowptr, bsum, N_);
    scatter_kernel<<<dim3((E_ + 255) / 256), blk, 0, stream>>>(src, dst, rowptr, csr_src, E_);

    // --- weight prep ---
    fuse_w_kernel<<<dim3(64), blk, 0, stream>>>(Win, bin_, Wout, bout, Wf_bf, bfused);
    WPtrs wp;
    wp.p[0] = Wte1; wp.p[1] = Wte2; wp.p[2] = WQ; wp.p[3] = WK; wp.p[4] = WV;
    wp.p[5] = W1;   wp.p[6] = W2;
    cvt_w_kernel<<<dim3(240), blk, 0, stream>>>(wp, wbf);

    // --- per-node TransformerEncoder (seq1 attn folded into Wf) ---
    gemm_bf16<1, 0, false><<<dim3(rowBlocks, 1), blk, 0, stream>>>(
        h, Wf_bf, bfused, bufB, nullptr, nullptr, nullptr, nullptr, 0.f, N_, 128, 128);   // t
    ln_residual_kernel<true><<<gRow, blk, 0, stream>>>(h, bufB, ln1g, ln1b, bufA, N_);    // x
    gemm_bf16<0, 0, true><<<dim3(rowBlocks, 4), blk, 0, stream>>>(
        bufA, Wte1_bf, bte1, bufD, nullptr, nullptr, nullptr, nullptr, 0.f, N_, 128, 512); // ff1
    gemm_bf16<0, 0, false><<<dim3(rowBlocks, 1), blk, 0, stream>>>(
        bufD, Wte2_bf, bte2, bufB, nullptr, nullptr, nullptr, nullptr, 0.f, N_, 512, 128); // ff
    ln_residual_kernel<false><<<gRow, blk, 0, stream>>>(bufA, bufB, ln2g, ln2b, bufC, N_); // hsub

    // --- graph multi-head attention ---
    gemm_bf16<0, 0, false><<<dim3(rowBlocks, 3), blk, 0, stream>>>(
        bufC, WQKV_bf, nullptr, bufD, nullptr, nullptr, nullptr, nullptr, 0.f, N_, 128, 384); // QKV
    attn_agg_kernel<<<gRow, blk, 0, stream>>>(
        rowptr, csr_src, bufD, bufC, bufA, N_);                                            // y1

    // --- BN1 (stats only; norm fused into W1-GEMM staging + W2-GEMM epilogue) ---
    bn_stats_kernel<<<dim3(512), blk, 0, stream>>>(bufA, stats, N_);

    // --- FFN + BN2 ---
    gemm_bf16<2, 0, true><<<dim3(rowBlocks, 2), blk, 0, stream>>>(
        bufA, W1_bf, b1, bufD, stats, bn1g, bn1b, nullptr, invn, N_, 128, 256);            // f1
    gemm_bf16<0, 2, false><<<dim3(rowBlocks, 1), blk, 0, stream>>>(
        bufD, W2_bf, b2, bufB, stats, bn1g, bn1b, bufA, invn, N_, 256, 128);               // y2
    bn_stats_kernel<<<dim3(512), blk, 0, stream>>>(bufB, stats + 256, N_);
    bn_norm_kernel<<<dim3((totElems / 4 + 255) / 256), blk, 0, stream>>>(
        bufB, stats + 256, bn2g, bn2b, (float*)d_out, invn, totElems / 4);
}

// Round 6
// 297.076 us; speedup vs baseline: 3.9617x; 1.0862x over previous
//
#include <hip/hip_runtime.h>
#include <hip/hip_bf16.h>

// GraphTransformerLayer on MI355X — round 6: LN/BN epilogue fusion + global_load_lds.
// N=50000 nodes, E=500000 edges, D=128, H=8, DH=16.

#define D_ 128

typedef __attribute__((ext_vector_type(8))) short short8;
typedef __attribute__((ext_vector_type(4))) short short4v;
typedef __attribute__((ext_vector_type(4))) float f32x4;

__device__ __forceinline__ float b2f(ushort u) {
    union { uint u32; float f; } x; x.u32 = ((uint)u) << 16; return x.f;
}
__device__ __forceinline__ ushort f2b(float f) {
    union { __hip_bfloat16 h; ushort u; } v; v.h = __float2bfloat16(f); return v.u;
}

// ---------------------------------------------------------------------------
// bf16 MFMA GEMM: C[n x M] = A[n x K] @ W[M x K]^T (+bias)(+relu)(+epilogues)
// 256 threads = 4 waves; tile 128x128; wave computes 64x64 (4x4 frags 16x16).
// LDS layout: [row][chunk^((row>>1)&3)] 16B chunks (2-way conflicts = free).
// AMODE: 0 = A bf16 via global_load_lds(16B, pre-swizzled source)
//        1 = A f32, reg-staged with convert
//        2 = A bf16 via global_load_lds + BN1 normalize at fragment read (K=128)
// EPI:   0 = bf16 store (+bias,+relu)
//        1 = LN(resid + acc + bias) row-norm -> bf16 (M=128, grid.y=1)
//        2 = y2 = acc + bias + BN1(y1res) -> bf16 + BN2 stats atomics (M=128)
// ---------------------------------------------------------------------------
template<int AMODE, int EPI, bool RELU, bool RESF32>
__global__ __launch_bounds__(256) void gemm_bf16(
    const void* __restrict__ Aptr, const ushort* __restrict__ W,
    const float* __restrict__ bias, void* __restrict__ C,
    const float* __restrict__ bn_in, float* __restrict__ bn_out,
    const float* __restrict__ bng, const float* __restrict__ bnb,
    const void* __restrict__ resid, const ushort* __restrict__ y1res,
    const float* __restrict__ lng, const float* __restrict__ lnb,
    float invn, int n, int K, int M)
{
    __shared__ ushort Abuf[128 * 32];
    __shared__ ushort Bbuf[128 * 32];
    __shared__ float s_sh[128], t_sh[128];

    const int t    = threadIdx.x;
    const int lane = t & 63;
    const int w    = t >> 6;
    const int r0   = blockIdx.x * 128;
    const int c0   = blockIdx.y * 128;
    const int wr   = (w >> 1) * 64;
    const int wc   = (w & 1) * 64;
    const int rl   = lane & 15;
    const int kh   = lane >> 4;

    if (AMODE == 2 || EPI == 2) {
        if (t < 128) {
            float m   = bn_in[t] * invn;
            float var = bn_in[128 + t] * invn - m * m;
            float rs  = rsqrtf(var + 1e-5f);
            float s   = rs * bng[t];
            s_sh[t] = s;
            t_sh[t] = bnb[t] - m * s;
        }
        __syncthreads();
    }

    f32x4 acc[4][4] = {};

    for (int kc = 0; kc < K; kc += 32) {
        if (AMODE == 1) {
            // reg staging with f32->bf16 convert
            short8 aval[2], bval[2];
            #pragma unroll
            for (int rep = 0; rep < 2; ++rep) {
                int i   = t + rep * 256;
                int row = i >> 2, ch = i & 3;
                int gr  = r0 + row;
                short8 v = {};
                if (gr < n) {
                    const float* Af = (const float*)Aptr;
                    float4 f0 = *reinterpret_cast<const float4*>(Af + (size_t)gr * K + kc + ch * 8);
                    float4 f1 = *reinterpret_cast<const float4*>(Af + (size_t)gr * K + kc + ch * 8 + 4);
                    v[0] = (short)f2b(f0.x); v[1] = (short)f2b(f0.y);
                    v[2] = (short)f2b(f0.z); v[3] = (short)f2b(f0.w);
                    v[4] = (short)f2b(f1.x); v[5] = (short)f2b(f1.y);
                    v[6] = (short)f2b(f1.z); v[7] = (short)f2b(f1.w);
                }
                aval[rep] = v;
                bval[rep] = *reinterpret_cast<const short8*>(W + (size_t)(c0 + row) * K + kc + ch * 8);
            }
            __syncthreads();   // prev iteration's LDS reads complete
            #pragma unroll
            for (int rep = 0; rep < 2; ++rep) {
                int i   = t + rep * 256;
                int row = i >> 2, ch = i & 3;
                int sw  = ch ^ ((row >> 1) & 3);
                *reinterpret_cast<short8*>(&Abuf[row * 32 + sw * 8]) = aval[rep];
                *reinterpret_cast<short8*>(&Bbuf[row * 32 + sw * 8]) = bval[rep];
            }
            __syncthreads();
        } else {
            __syncthreads();   // prev iteration's LDS reads complete
            // linear LDS dest + inverse-swizzled global source (involution)
            #pragma unroll
            for (int rep = 0; rep < 2; ++rep) {
                int s   = t + rep * 256;       // lds 16B slot
                int row = s >> 2, pos = s & 3;
                int ch  = pos ^ ((row >> 1) & 3);
                const ushort* srcA = (const ushort*)Aptr + (size_t)(r0 + row) * K + kc + ch * 8;
                const ushort* srcB = W + (size_t)(c0 + row) * K + kc + ch * 8;
                __builtin_amdgcn_global_load_lds(
                    (const __attribute__((address_space(1))) void*)srcA,
                    (__attribute__((address_space(3))) void*)&Abuf[s * 8], 16, 0, 0);
                __builtin_amdgcn_global_load_lds(
                    (const __attribute__((address_space(1))) void*)srcB,
                    (__attribute__((address_space(3))) void*)&Bbuf[s * 8], 16, 0, 0);
            }
            __syncthreads();
        }

        short8 af[4], bfr[4];
        #pragma unroll
        for (int m = 0; m < 4; ++m) {
            int row = wr + m * 16 + rl;
            af[m] = *reinterpret_cast<const short8*>(&Abuf[row * 32 + (kh ^ ((row >> 1) & 3)) * 8]);
        }
        if (AMODE == 2) {
            // stored chunk at read-pos is original chunk kh -> channels kc+kh*8+q
            #pragma unroll
            for (int m = 0; m < 4; ++m) {
                short8 v = af[m];
                #pragma unroll
                for (int q = 0; q < 8; ++q) {
                    int cch = kc + kh * 8 + q;
                    v[q] = (short)f2b(fmaf(b2f((ushort)v[q]), s_sh[cch], t_sh[cch]));
                }
                af[m] = v;
            }
        }
        #pragma unroll
        for (int nn = 0; nn < 4; ++nn) {
            int col = wc + nn * 16 + rl;
            bfr[nn] = *reinterpret_cast<const short8*>(&Bbuf[col * 32 + (kh ^ ((col >> 1) & 3)) * 8]);
        }
        #pragma unroll
        for (int m = 0; m < 4; ++m)
            #pragma unroll
            for (int nn = 0; nn < 4; ++nn)
                acc[m][nn] = __builtin_amdgcn_mfma_f32_16x16x32_bf16(
                    bfr[nn], af[m], acc[m][nn], 0, 0, 0);
    }

    const int ch4 = kh * 4;

    if (EPI == 1) {
        // LN(resid + acc + bias) over the 128-col row (c0 == 0, M == 128)
        __shared__ float lnS[128][2], lnS2[128][2];
        float4 bb[4];
        #pragma unroll
        for (int nn = 0; nn < 4; ++nn)
            bb[nn] = *reinterpret_cast<const float4*>(bias + wc + nn * 16 + ch4);
        #pragma unroll
        for (int m = 0; m < 4; ++m) {
            int r = r0 + wr + m * 16 + rl;
            float s = 0.f, s2 = 0.f;
            #pragma unroll
            for (int nn = 0; nn < 4; ++nn) {
                int c = wc + nn * 16 + ch4;
                float rv[4] = {0.f, 0.f, 0.f, 0.f};
                if (r < n) {
                    if (RESF32) {
                        float4 f = *reinterpret_cast<const float4*>((const float*)resid + (size_t)r * 128 + c);
                        rv[0] = f.x; rv[1] = f.y; rv[2] = f.z; rv[3] = f.w;
                    } else {
                        short4v f = *reinterpret_cast<const short4v*>((const ushort*)resid + (size_t)r * 128 + c);
                        rv[0] = b2f((ushort)f[0]); rv[1] = b2f((ushort)f[1]);
                        rv[2] = b2f((ushort)f[2]); rv[3] = b2f((ushort)f[3]);
                    }
                }
                float bj[4] = {bb[nn].x, bb[nn].y, bb[nn].z, bb[nn].w};
                #pragma unroll
                for (int j = 0; j < 4; ++j) {
                    float o = acc[m][nn][j] + bj[j] + rv[j];
                    acc[m][nn][j] = o;
                    s += o; s2 += o * o;
                }
            }
            s  += __shfl_xor(s, 16);  s  += __shfl_xor(s, 32);
            s2 += __shfl_xor(s2, 16); s2 += __shfl_xor(s2, 32);
            if (kh == 0) {
                lnS[wr + m * 16 + rl][w & 1]  = s;
                lnS2[wr + m * 16 + rl][w & 1] = s2;
            }
        }
        __syncthreads();
        #pragma unroll
        for (int m = 0; m < 4; ++m) {
            int rloc = wr + m * 16 + rl;
            int r = r0 + rloc;
            float S  = lnS[rloc][0] + lnS[rloc][1];
            float S2 = lnS2[rloc][0] + lnS2[rloc][1];
            float mean = S * (1.f / 128.f);
            float var  = S2 * (1.f / 128.f) - mean * mean;
            float rs   = rsqrtf(var + 1e-5f);
            if (r >= n) continue;
            #pragma unroll
            for (int nn = 0; nn < 4; ++nn) {
                int c = wc + nn * 16 + ch4;
                float4 gv = *reinterpret_cast<const float4*>(lng + c);
                float4 bv = *reinterpret_cast<const float4*>(lnb + c);
                float gj[4] = {gv.x, gv.y, gv.z, gv.w};
                float bj[4] = {bv.x, bv.y, bv.z, bv.w};
                short4v p;
                #pragma unroll
                for (int j = 0; j < 4; ++j)
                    p[j] = (short)f2b((acc[m][nn][j] - mean) * rs * gj[j] + bj[j]);
                *reinterpret_cast<short4v*>((ushort*)C + (size_t)r * 128 + c) = p;
            }
        }
        return;
    }

    if (EPI == 2) {
        // y2 = acc + bias + BN1(y1res); store bf16; BN2 stats atomics (M == 128)
        __shared__ float csum[128], csum2[128];
        if (t < 128) { csum[t] = 0.f; csum2[t] = 0.f; }
        __syncthreads();
        float ps[4][4] = {};   // [nn][j] col partials
        float ps2[4][4] = {};
        #pragma unroll
        for (int m = 0; m < 4; ++m) {
            int r = r0 + wr + m * 16 + rl;
            bool ok = r < n;
            #pragma unroll
            for (int nn = 0; nn < 4; ++nn) {
                int c = wc + nn * 16 + ch4;
                float4 bb = *reinterpret_cast<const float4*>(bias + c);
                float bj[4] = {bb.x, bb.y, bb.z, bb.w};
                short4v yv = {};
                if (ok) yv = *reinterpret_cast<const short4v*>(y1res + (size_t)r * 128 + c);
                short4v p;
                #pragma unroll
                for (int j = 0; j < 4; ++j) {
                    float o = 0.f;
                    if (ok) {
                        o = acc[m][nn][j] + bj[j]
                          + fmaf(b2f((ushort)yv[j]), s_sh[c + j], t_sh[c + j]);
                    }
                    ps[nn][j] += o; ps2[nn][j] += o * o;
                    p[j] = (short)f2b(o);
                }
                if (ok)
                    *reinterpret_cast<short4v*>((ushort*)C + (size_t)r * 128 + c) = p;
            }
        }
        // reduce over the 16 rl lanes of each kh group
        #pragma unroll
        for (int nn = 0; nn < 4; ++nn)
            #pragma unroll
            for (int j = 0; j < 4; ++j) {
                float a = ps[nn][j], b = ps2[nn][j];
                #pragma unroll
                for (int o2 = 1; o2 < 16; o2 <<= 1) {
                    a += __shfl_xor(a, o2);
                    b += __shfl_xor(b, o2);
                }
                if (rl == 0) {
                    int c = wc + nn * 16 + ch4 + j;
                    atomicAdd(&csum[c], a);
                    atomicAdd(&csum2[c], b);
                }
            }
        __syncthreads();
        if (t < 128) {
            atomicAdd(bn_out + t, csum[t]);
            atomicAdd(bn_out + 128 + t, csum2[t]);
        }
        return;
    }

    // EPI == 0
    #pragma unroll
    for (int m = 0; m < 4; ++m) {
        int r = r0 + wr + m * 16 + rl;
        if (r >= n) continue;
        #pragma unroll
        for (int nn = 0; nn < 4; ++nn) {
            int c = c0 + wc + nn * 16 + ch4;
            f32x4 vacc = acc[m][nn];
            float4 bb = make_float4(0.f, 0.f, 0.f, 0.f);
            if (bias) bb = *reinterpret_cast<const float4*>(bias + c);
            float o0 = vacc[0] + bb.x, o1 = vacc[1] + bb.y;
            float o2 = vacc[2] + bb.z, o3 = vacc[3] + bb.w;
            if (RELU) {
                o0 = fmaxf(o0, 0.f); o1 = fmaxf(o1, 0.f);
                o2 = fmaxf(o2, 0.f); o3 = fmaxf(o3, 0.f);
            }
            short4v p;
            p[0] = (short)f2b(o0); p[1] = (short)f2b(o1);
            p[2] = (short)f2b(o2); p[3] = (short)f2b(o3);
            *reinterpret_cast<short4v*>((ushort*)C + (size_t)r * M + c) = p;
        }
    }
}

// ---------------------------------------------------------------------------
// CSR build
// ---------------------------------------------------------------------------
__global__ void hist_kernel(const int* __restrict__ dst, int* __restrict__ cnt, int E_)
{
    int e = blockIdx.x * blockDim.x + threadIdx.x;
    if (e < E_) atomicAdd(cnt + dst[e], 1);
}

__global__ __launch_bounds__(256) void scan_block_kernel(
    int* __restrict__ data, int* __restrict__ bsum, int n)
{
    __shared__ int tmp[256];
    int i = blockIdx.x * 256 + threadIdx.x;
    int v = (i < n) ? data[i] : 0;
    tmp[threadIdx.x] = v;
    __syncthreads();
    #pragma unroll
    for (int o = 1; o < 256; o <<= 1) {
        int y = (threadIdx.x >= o) ? tmp[threadIdx.x - o] : 0;
        __syncthreads();
        tmp[threadIdx.x] += y;
        __syncthreads();
    }
    if (i < n) data[i] = tmp[threadIdx.x] - v;
    if (threadIdx.x == 255) bsum[blockIdx.x] = tmp[255];
}

__global__ __launch_bounds__(256) void scan_bsum_kernel(int* __restrict__ bsum, int nb)
{
    __shared__ int tmp[256];
    int v = (threadIdx.x < nb) ? bsum[threadIdx.x] : 0;
    tmp[threadIdx.x] = v;
    __syncthreads();
    #pragma unroll
    for (int o = 1; o < 256; o <<= 1) {
        int y = (threadIdx.x >= o) ? tmp[threadIdx.x - o] : 0;
        __syncthreads();
        tmp[threadIdx.x] += y;
        __syncthreads();
    }
    if (threadIdx.x < nb) bsum[threadIdx.x] = tmp[threadIdx.x] - v;
}

__global__ void add_off_kernel(int* __restrict__ data, const int* __restrict__ bsum, int n)
{
    int i = blockIdx.x * blockDim.x + threadIdx.x;
    if (i < n) data[i] += bsum[i >> 8];
}

__global__ void scatter_kernel(const int* __restrict__ src, const int* __restrict__ dst,
                               int* __restrict__ rowptr, int* __restrict__ csr_src, int E_)
{
    int e = blockIdx.x * blockDim.x + threadIdx.x;
    if (e >= E_) return;
    int pos = atomicAdd(rowptr + dst[e], 1);
    csr_src[pos] = src[e];
}

// ---------------------------------------------------------------------------
// Gather attention. One wave per node = 4 edge-slots x 16 lanes (8 ch/lane).
// QKV interleaved [N][384]: Q at +0, K at +128, V at +256.
// Writes y1 = hsub + wV/z (bf16).
// ---------------------------------------------------------------------------
__global__ __launch_bounds__(256) void attn_agg_kernel(
    const int* __restrict__ rowptr, const int* __restrict__ csr_src,
    const ushort* __restrict__ QKV, const ushort* __restrict__ hsub,
    ushort* __restrict__ out, int n)
{
    int node = (blockIdx.x * blockDim.x + threadIdx.x) >> 6;
    if (node >= n) return;
    int lane = threadIdx.x & 63;
    int g    = lane >> 4;
    int sub  = lane & 15;
    int start = node ? rowptr[node - 1] : 0;
    int end   = rowptr[node];

    short8 q8 = *reinterpret_cast<const short8*>(QKV + (size_t)node * 384 + sub * 8);
    float q[8];
    #pragma unroll
    for (int i = 0; i < 8; ++i) q[i] = b2f((ushort)q8[i]);

    float acc[8] = {};
    float zh = 0.f;
    for (int j = start; j < end; j += 4) {
        int idx  = j + g;
        bool act = idx < end;
        int s = csr_src[act ? idx : start];
        const ushort* kvp = QKV + (size_t)s * 384;
        short8 k8 = *reinterpret_cast<const short8*>(kvp + 128 + sub * 8);
        float p = 0.f;
        #pragma unroll
        for (int i = 0; i < 8; ++i) p = fmaf(b2f((ushort)k8[i]), q[i], p);
        p += __shfl_xor(p, 1);
        float sc = act ? __expf(fminf(fmaxf(p * 0.25f, -5.f), 5.f)) : 0.f;
        short8 v8 = *reinterpret_cast<const short8*>(kvp + 256 + sub * 8);
        #pragma unroll
        for (int i = 0; i < 8; ++i) acc[i] = fmaf(sc, b2f((ushort)v8[i]), acc[i]);
        zh += sc;
    }
    #pragma unroll
    for (int i = 0; i < 8; ++i) {
        acc[i] += __shfl_xor(acc[i], 16);
        acc[i] += __shfl_xor(acc[i], 32);
    }
    zh += __shfl_xor(zh, 16);
    zh += __shfl_xor(zh, 32);

    if (g == 0) {
        short8 h8 = *reinterpret_cast<const short8*>(hsub + (size_t)node * D_ + sub * 8);
        float inv = 1.f / zh;
        short8 o;
        #pragma unroll
        for (int i = 0; i < 8; ++i)
            o[i] = (short)f2b(b2f((ushort)h8[i]) + acc[i] * inv);
        *reinterpret_cast<short8*>(out + (size_t)node * D_ + sub * 8) = o;
    }
}

// ---------------------------------------------------------------------------
// BN stats over bf16 input: sums[c], sums[128+c].
// ---------------------------------------------------------------------------
__global__ __launch_bounds__(256) void bn_stats_kernel(
    const ushort* __restrict__ x, float* __restrict__ sums, int n)
{
    int c    = threadIdx.x & 127;
    int half = threadIdx.x >> 7;
    float s = 0.f, s2 = 0.f;
    for (int r = blockIdx.x * 2 + half; r < n; r += gridDim.x * 2) {
        float v = b2f(x[(size_t)r * D_ + c]);
        s += v; s2 += v * v;
    }
    __shared__ float ls[256], ls2[256];
    ls[threadIdx.x] = s; ls2[threadIdx.x] = s2;
    __syncthreads();
    if (half == 0) {
        s  += ls[threadIdx.x + 128];
        s2 += ls2[threadIdx.x + 128];
        atomicAdd(sums + c, s);
        atomicAdd(sums + 128 + c, s2);
    }
}

// final BN: bf16 in -> f32 out, 4 elems/thread
__global__ void bn_norm_kernel(const ushort* __restrict__ x,
                               const float* __restrict__ stats,
                               const float* __restrict__ g, const float* __restrict__ b,
                               float* __restrict__ out, float invn, int total4)
{
    int i = blockIdx.x * blockDim.x + threadIdx.x;
    if (i >= total4) return;
    int cb = (i << 2) & 127;
    short4v v = reinterpret_cast<const short4v*>(x)[i];
    float4 o;
    float r[4];
    #pragma unroll
    for (int q = 0; q < 4; ++q) {
        int c = cb + q;
        float m   = stats[c] * invn;
        float var = stats[128 + c] * invn - m * m;
        float rs  = rsqrtf(var + 1e-5f);
        r[q] = (b2f((ushort)v[q]) - m) * rs * g[c] + b[c];
    }
    o.x = r[0]; o.y = r[1]; o.z = r[2]; o.w = r[3];
    reinterpret_cast<float4*>(out)[i] = o;
}

// ---------------------------------------------------------------------------
// Weight prep: Wf = bf16(Wout @ WinV), bfused = Wout @ binV + bout.
// ---------------------------------------------------------------------------
__global__ __launch_bounds__(256) void fuse_w_kernel(
    const float* __restrict__ Win, const float* __restrict__ bin_,
    const float* __restrict__ Wout, const float* __restrict__ bout,
    ushort* __restrict__ Wf, float* __restrict__ bf)
{
    int idx = blockIdx.x * 256 + threadIdx.x;   // 16384 total
    int i = idx >> 7, c = idx & 127;
    const float* WinV = Win + 256 * 128;
    float s = 0.f;
    for (int j = 0; j < 128; ++j)
        s = fmaf(Wout[i * 128 + j], WinV[j * 128 + c], s);
    Wf[idx] = f2b(s);
    if (c == 0) {
        float tb = bout[i];
        for (int j = 0; j < 128; ++j)
            tb = fmaf(Wout[i * 128 + j], bin_[256 + j], tb);
        bf[i] = tb;
    }
}

// bf16 conversion of the 7 remaining weight mats (245760 elems, 4/thread)
struct WPtrs { const float* p[7]; };

__global__ __launch_bounds__(256) void cvt_w_kernel(WPtrs wp, ushort* __restrict__ out)
{
    const int off[8] = {0, 65536, 131072, 147456, 163840, 180224, 212992, 245760};
    int e0 = (blockIdx.x * 256 + threadIdx.x) * 4;
    if (e0 >= 245760) return;
    int s = 0;
    #pragma unroll
    for (int j = 1; j < 7; ++j) if (e0 >= off[j]) s = j;
    float4 f = *reinterpret_cast<const float4*>(wp.p[s] + (e0 - off[s]));
    short4v o;
    o[0] = (short)f2b(f.x); o[1] = (short)f2b(f.y);
    o[2] = (short)f2b(f.z); o[3] = (short)f2b(f.w);
    *reinterpret_cast<short4v*>(out + e0) = o;
}

// ---------------------------------------------------------------------------
extern "C" void kernel_launch(void* const* d_in, const int* in_sizes, int n_in,
                              void* d_out, int out_size, void* d_ws, size_t ws_size,
                              hipStream_t stream)
{
    const float* h    = (const float*)d_in[0];
    const int*   src  = (const int*)d_in[1];
    const int*   dst  = (const int*)d_in[2];
    const float* Win  = (const float*)d_in[3];
    const float* bin_ = (const float*)d_in[4];
    const float* Wout = (const float*)d_in[5];
    const float* bout = (const float*)d_in[6];
    const float* Wte1 = (const float*)d_in[7];
    const float* bte1 = (const float*)d_in[8];
    const float* Wte2 = (const float*)d_in[9];
    const float* bte2 = (const float*)d_in[10];
    const float* ln1g = (const float*)d_in[11];
    const float* ln1b = (const float*)d_in[12];
    const float* ln2g = (const float*)d_in[13];
    const float* ln2b = (const float*)d_in[14];
    const float* WQ   = (const float*)d_in[15];
    const float* WK   = (const float*)d_in[16];
    const float* WV   = (const float*)d_in[17];
    const float* W1   = (const float*)d_in[18];
    const float* b1   = (const float*)d_in[19];
    const float* W2   = (const float*)d_in[20];
    const float* b2   = (const float*)d_in[21];
    const float* bn1g = (const float*)d_in[22];
    const float* bn1b = (const float*)d_in[23];
    const float* bn2g = (const float*)d_in[24];
    const float* bn2b = (const float*)d_in[25];

    const int N_ = in_sizes[0] / D_;
    const int E_ = in_sizes[1];
    const size_t S2 = (size_t)N_ * D_ / 2;   // float-units of one N x 128 bf16 buffer

    float* ws = (float*)d_ws;
    // layout (float units):
    //   [0, S2)        bufA  (bf16 NxD)
    //   [S2, 2S2)      bufB  (bf16 NxD)
    //   [2S2, 3S2)     bufC  (bf16 NxD)
    //   [3S2, 7S2)     bufD  (bf16 Nx512 max: ff1/QKV/f1)
    //   [7S2, ...)     wbf (131072 f), bfused (128), stats (512), ints
    size_t off_tail = 7 * S2;
    size_t need = (off_tail + 131072 + 128 + 512) * sizeof(float)
                + (size_t)(N_ + E_ + 256) * sizeof(int) + 4096;
    if (ws_size < need) return;

    ushort* bufA   = (ushort*)ws;
    ushort* bufB   = (ushort*)(ws + S2);
    ushort* bufC   = (ushort*)(ws + 2 * S2);
    ushort* bufD   = (ushort*)(ws + 3 * S2);
    ushort* wbf    = (ushort*)(ws + off_tail);        // 262144 bf16 = 131072 f
    float*  bfused = ws + off_tail + 131072;          // 128
    float*  stats  = bfused + 128;                    // 512
    int* rowptr  = (int*)(stats + 512);               // N
    int* csr_src = rowptr + N_;                       // E
    int* bsum    = csr_src + E_;                      // 256

    const ushort* Wte1_bf = wbf;
    const ushort* Wte2_bf = wbf + 65536;
    const ushort* WQKV_bf = wbf + 131072;             // [WQ;WK;WV] 384x128
    const ushort* W1_bf   = wbf + 180224;
    const ushort* W2_bf   = wbf + 212992;
    ushort*       Wf_bf   = wbf + 245760;             // fused Wout@WinV

    dim3 blk(256);
    const int rowBlocks = (N_ + 127) / 128;
    const int totElems  = N_ * D_;
    const dim3 gRow((N_ + 3) / 4);
    const int nb = (N_ + 255) / 256;
    const float invn = 1.f / (float)N_;

    hipMemsetAsync(stats, 0, 512 * sizeof(float), stream);
    hipMemsetAsync(rowptr, 0, (size_t)N_ * sizeof(int), stream);

    // --- CSR build ---
    hist_kernel<<<dim3((E_ + 255) / 256), blk, 0, stream>>>(dst, rowptr, E_);
    scan_block_kernel<<<dim3(nb), blk, 0, stream>>>(rowptr, bsum, N_);
    scan_bsum_kernel<<<dim3(1), blk, 0, stream>>>(bsum, nb);
    add_off_kernel<<<dim3(nb), blk, 0, stream>>>(rowptr, bsum, N_);
    scatter_kernel<<<dim3((E_ + 255) / 256), blk, 0, stream>>>(src, dst, rowptr, csr_src, E_);

    // --- weight prep ---
    fuse_w_kernel<<<dim3(64), blk, 0, stream>>>(Win, bin_, Wout, bout, Wf_bf, bfused);
    WPtrs wp;
    wp.p[0] = Wte1; wp.p[1] = Wte2; wp.p[2] = WQ; wp.p[3] = WK; wp.p[4] = WV;
    wp.p[5] = W1;   wp.p[6] = W2;
    cvt_w_kernel<<<dim3(240), blk, 0, stream>>>(wp, wbf);

    // --- per-node TransformerEncoder (seq1 attn folded into Wf) ---
    // x = LN1(h + h@Wf^T + bfused)  (LN fused in epilogue)
    gemm_bf16<1, 1, false, true><<<dim3(rowBlocks, 1), blk, 0, stream>>>(
        h, Wf_bf, bfused, bufA, nullptr, nullptr, nullptr, nullptr,
        h, nullptr, ln1g, ln1b, 0.f, N_, 128, 128);
    // ff1 = relu(x @ Wte1^T + bte1)
    gemm_bf16<0, 0, true, false><<<dim3(rowBlocks, 4), blk, 0, stream>>>(
        bufA, Wte1_bf, bte1, bufD, nullptr, nullptr, nullptr, nullptr,
        nullptr, nullptr, nullptr, nullptr, 0.f, N_, 128, 512);
    // hsub = LN2(x + ff1 @ Wte2^T + bte2)  (LN fused in epilogue)
    gemm_bf16<0, 1, false, false><<<dim3(rowBlocks, 1), blk, 0, stream>>>(
        bufD, Wte2_bf, bte2, bufC, nullptr, nullptr, nullptr, nullptr,
        bufA, nullptr, ln2g, ln2b, 0.f, N_, 512, 128);

    // --- graph multi-head attention ---
    gemm_bf16<0, 0, false, false><<<dim3(rowBlocks, 3), blk, 0, stream>>>(
        bufC, WQKV_bf, nullptr, bufD, nullptr, nullptr, nullptr, nullptr,
        nullptr, nullptr, nullptr, nullptr, 0.f, N_, 128, 384);
    attn_agg_kernel<<<gRow, blk, 0, stream>>>(
        rowptr, csr_src, bufD, bufC, bufA, N_);                          // y1 -> A

    // --- BN1 stats (norm fused into W1 frag-read + W2 epilogue) ---
    bn_stats_kernel<<<dim3(512), blk, 0, stream>>>(bufA, stats, N_);

    // --- FFN + BN2 ---
    // f1 = relu(BN1(y1) @ W1^T + b1)
    gemm_bf16<2, 0, true, false><<<dim3(rowBlocks, 2), blk, 0, stream>>>(
        bufA, W1_bf, b1, bufD, stats, nullptr, bn1g, bn1b,
        nullptr, nullptr, nullptr, nullptr, invn, N_, 128, 256);
    // y2 = BN1(y1) + f1 @ W2^T + b2 ; BN2 stats fused
    gemm_bf16<0, 2, false, false><<<dim3(rowBlocks, 1), blk, 0, stream>>>(
        bufD, W2_bf, b2, bufB, stats, stats + 256, bn1g, bn1b,
        nullptr, bufA, nullptr, nullptr, invn, N_, 256, 128);
    bn_norm_kernel<<<dim3((totElems / 4 + 255) / 256), blk, 0, stream>>>(
        bufB, stats + 256, bn2g, bn2b, (float*)d_out, invn, totElems / 4);
}

// Round 7
// 282.944 us; speedup vs baseline: 4.1596x; 1.0499x over previous
//
#include <hip/hip_runtime.h>
#include <hip/hip_bf16.h>

// GraphTransformerLayer on MI355X — round 7: 8-wave GEMM blocks + head-per-lane attn.
// N=50000 nodes, E=500000 edges, D=128, H=8, DH=16.

#define D_ 128

typedef __attribute__((ext_vector_type(8))) short short8;
typedef __attribute__((ext_vector_type(4))) short short4v;
typedef __attribute__((ext_vector_type(4))) float f32x4;

__device__ __forceinline__ float b2f(ushort u) {
    union { uint u32; float f; } x; x.u32 = ((uint)u) << 16; return x.f;
}
__device__ __forceinline__ ushort f2b(float f) {
    union { __hip_bfloat16 h; ushort u; } v; v.h = __float2bfloat16(f); return v.u;
}

// ---------------------------------------------------------------------------
// bf16 MFMA GEMM: C[n x M] = A[n x K] @ W[M x K]^T (+bias)(+relu)(+epilogues)
// 512 threads = 8 waves; tile 128x128; wave computes 32x64 (2x4 frags 16x16).
// LDS layout: [row][chunk^((row>>1)&3)] 16B chunks (2-way conflicts = free).
// AMODE: 0 = A bf16 via global_load_lds(16B, pre-swizzled source)
//        1 = A f32, reg-staged with convert
//        2 = A bf16 via global_load_lds + BN1 normalize at fragment read (K=128)
// EPI:   0 = bf16 store (+bias,+relu)
//        1 = LN(resid + acc + bias) row-norm -> bf16 (M=128, grid.y=1)
//        2 = y2 = acc + bias + BN1(y1res) -> bf16 + BN2 stats atomics (M=128)
// ---------------------------------------------------------------------------
template<int AMODE, int EPI, bool RELU, bool RESF32>
__global__ __launch_bounds__(512) void gemm_bf16(
    const void* __restrict__ Aptr, const ushort* __restrict__ W,
    const float* __restrict__ bias, void* __restrict__ C,
    const float* __restrict__ bn_in, float* __restrict__ bn_out,
    const float* __restrict__ bng, const float* __restrict__ bnb,
    const void* __restrict__ resid, const ushort* __restrict__ y1res,
    const float* __restrict__ lng, const float* __restrict__ lnb,
    float invn, int n, int K, int M)
{
    __shared__ ushort Abuf[128 * 32];
    __shared__ ushort Bbuf[128 * 32];
    __shared__ float s_sh[128], t_sh[128];

    const int t    = threadIdx.x;        // 0..511
    const int lane = t & 63;
    const int w    = t >> 6;             // 0..7
    const int r0   = blockIdx.x * 128;
    const int c0   = blockIdx.y * 128;
    const int wr   = (w >> 1) * 32;      // 0,32,64,96
    const int wc   = (w & 1) * 64;       // 0,64
    const int rl   = lane & 15;
    const int kh   = lane >> 4;          // 16B k-chunk 0..3

    if (AMODE == 2 || EPI == 2) {
        if (t < 128) {
            float m   = bn_in[t] * invn;
            float var = bn_in[128 + t] * invn - m * m;
            float rs  = rsqrtf(var + 1e-5f);
            float s   = rs * bng[t];
            s_sh[t] = s;
            t_sh[t] = bnb[t] - m * s;
        }
        __syncthreads();
    }

    f32x4 acc[2][4] = {};                // [m][nn]

    for (int kc = 0; kc < K; kc += 32) {
        const int row = t >> 2, pos = t & 3;
        if (AMODE == 1) {
            // reg staging with f32->bf16 convert, 1 chunk/thread
            const int ch = pos;
            int gr = r0 + row;
            short8 aval = {};
            if (gr < n) {
                const float* Af = (const float*)Aptr;
                float4 f0 = *reinterpret_cast<const float4*>(Af + (size_t)gr * K + kc + ch * 8);
                float4 f1 = *reinterpret_cast<const float4*>(Af + (size_t)gr * K + kc + ch * 8 + 4);
                aval[0] = (short)f2b(f0.x); aval[1] = (short)f2b(f0.y);
                aval[2] = (short)f2b(f0.z); aval[3] = (short)f2b(f0.w);
                aval[4] = (short)f2b(f1.x); aval[5] = (short)f2b(f1.y);
                aval[6] = (short)f2b(f1.z); aval[7] = (short)f2b(f1.w);
            }
            short8 bval = *reinterpret_cast<const short8*>(W + (size_t)(c0 + row) * K + kc + ch * 8);
            __syncthreads();   // prev iteration's LDS reads complete
            int sw = ch ^ ((row >> 1) & 3);
            *reinterpret_cast<short8*>(&Abuf[row * 32 + sw * 8]) = aval;
            *reinterpret_cast<short8*>(&Bbuf[row * 32 + sw * 8]) = bval;
            __syncthreads();
        } else {
            __syncthreads();   // prev iteration's LDS reads complete
            // linear LDS dest + inverse-swizzled global source (involution)
            const int ch = pos ^ ((row >> 1) & 3);
            const ushort* srcA = (const ushort*)Aptr + (size_t)(r0 + row) * K + kc + ch * 8;
            const ushort* srcB = W + (size_t)(c0 + row) * K + kc + ch * 8;
            __builtin_amdgcn_global_load_lds(
                (const __attribute__((address_space(1))) void*)srcA,
                (__attribute__((address_space(3))) void*)&Abuf[t * 8], 16, 0, 0);
            __builtin_amdgcn_global_load_lds(
                (const __attribute__((address_space(1))) void*)srcB,
                (__attribute__((address_space(3))) void*)&Bbuf[t * 8], 16, 0, 0);
            __syncthreads();
        }

        short8 af[2], bfr[4];
        #pragma unroll
        for (int m = 0; m < 2; ++m) {
            int rr = wr + m * 16 + rl;
            af[m] = *reinterpret_cast<const short8*>(&Abuf[rr * 32 + (kh ^ ((rr >> 1) & 3)) * 8]);
        }
        if (AMODE == 2) {
            // stored chunk at read-pos is original chunk kh -> channels kc+kh*8+q
            #pragma unroll
            for (int m = 0; m < 2; ++m) {
                short8 v = af[m];
                #pragma unroll
                for (int q = 0; q < 8; ++q) {
                    int cch = kc + kh * 8 + q;
                    v[q] = (short)f2b(fmaf(b2f((ushort)v[q]), s_sh[cch], t_sh[cch]));
                }
                af[m] = v;
            }
        }
        #pragma unroll
        for (int nn = 0; nn < 4; ++nn) {
            int col = wc + nn * 16 + rl;
            bfr[nn] = *reinterpret_cast<const short8*>(&Bbuf[col * 32 + (kh ^ ((col >> 1) & 3)) * 8]);
        }
        #pragma unroll
        for (int m = 0; m < 2; ++m)
            #pragma unroll
            for (int nn = 0; nn < 4; ++nn)
                acc[m][nn] = __builtin_amdgcn_mfma_f32_16x16x32_bf16(
                    bfr[nn], af[m], acc[m][nn], 0, 0, 0);
    }

    const int ch4 = kh * 4;

    if (EPI == 1) {
        // LN(resid + acc + bias) over the 128-col row (c0 == 0, M == 128)
        __shared__ float lnS[128][2], lnS2[128][2];
        float4 bb[4];
        #pragma unroll
        for (int nn = 0; nn < 4; ++nn)
            bb[nn] = *reinterpret_cast<const float4*>(bias + wc + nn * 16 + ch4);
        #pragma unroll
        for (int m = 0; m < 2; ++m) {
            int r = r0 + wr + m * 16 + rl;
            float s = 0.f, s2 = 0.f;
            #pragma unroll
            for (int nn = 0; nn < 4; ++nn) {
                int c = wc + nn * 16 + ch4;
                float rv[4] = {0.f, 0.f, 0.f, 0.f};
                if (r < n) {
                    if (RESF32) {
                        float4 f = *reinterpret_cast<const float4*>((const float*)resid + (size_t)r * 128 + c);
                        rv[0] = f.x; rv[1] = f.y; rv[2] = f.z; rv[3] = f.w;
                    } else {
                        short4v f = *reinterpret_cast<const short4v*>((const ushort*)resid + (size_t)r * 128 + c);
                        rv[0] = b2f((ushort)f[0]); rv[1] = b2f((ushort)f[1]);
                        rv[2] = b2f((ushort)f[2]); rv[3] = b2f((ushort)f[3]);
                    }
                }
                float bj[4] = {bb[nn].x, bb[nn].y, bb[nn].z, bb[nn].w};
                #pragma unroll
                for (int j = 0; j < 4; ++j) {
                    float o = acc[m][nn][j] + bj[j] + rv[j];
                    acc[m][nn][j] = o;
                    s += o; s2 += o * o;
                }
            }
            s  += __shfl_xor(s, 16);  s  += __shfl_xor(s, 32);
            s2 += __shfl_xor(s2, 16); s2 += __shfl_xor(s2, 32);
            if (kh == 0) {
                lnS[wr + m * 16 + rl][w & 1]  = s;
                lnS2[wr + m * 16 + rl][w & 1] = s2;
            }
        }
        __syncthreads();
        #pragma unroll
        for (int m = 0; m < 2; ++m) {
            int rloc = wr + m * 16 + rl;
            int r = r0 + rloc;
            float S  = lnS[rloc][0] + lnS[rloc][1];
            float S2 = lnS2[rloc][0] + lnS2[rloc][1];
            float mean = S * (1.f / 128.f);
            float var  = S2 * (1.f / 128.f) - mean * mean;
            float rs   = rsqrtf(var + 1e-5f);
            if (r >= n) continue;
            #pragma unroll
            for (int nn = 0; nn < 4; ++nn) {
                int c = wc + nn * 16 + ch4;
                float4 gv = *reinterpret_cast<const float4*>(lng + c);
                float4 bv = *reinterpret_cast<const float4*>(lnb + c);
                float gj[4] = {gv.x, gv.y, gv.z, gv.w};
                float bj[4] = {bv.x, bv.y, bv.z, bv.w};
                short4v p;
                #pragma unroll
                for (int j = 0; j < 4; ++j)
                    p[j] = (short)f2b((acc[m][nn][j] - mean) * rs * gj[j] + bj[j]);
                *reinterpret_cast<short4v*>((ushort*)C + (size_t)r * 128 + c) = p;
            }
        }
        return;
    }

    if (EPI == 2) {
        // y2 = acc + bias + BN1(y1res); store bf16; BN2 stats atomics (M == 128)
        __shared__ float csum[128], csum2[128];
        if (t < 128) { csum[t] = 0.f; csum2[t] = 0.f; }
        __syncthreads();
        float ps[4][4] = {};   // [nn][j] col partials
        float ps2[4][4] = {};
        #pragma unroll
        for (int m = 0; m < 2; ++m) {
            int r = r0 + wr + m * 16 + rl;
            bool ok = r < n;
            #pragma unroll
            for (int nn = 0; nn < 4; ++nn) {
                int c = wc + nn * 16 + ch4;
                float4 bb = *reinterpret_cast<const float4*>(bias + c);
                float bj[4] = {bb.x, bb.y, bb.z, bb.w};
                short4v yv = {};
                if (ok) yv = *reinterpret_cast<const short4v*>(y1res + (size_t)r * 128 + c);
                short4v p;
                #pragma unroll
                for (int j = 0; j < 4; ++j) {
                    float o = 0.f;
                    if (ok) {
                        o = acc[m][nn][j] + bj[j]
                          + fmaf(b2f((ushort)yv[j]), s_sh[c + j], t_sh[c + j]);
                    }
                    ps[nn][j] += o; ps2[nn][j] += o * o;
                    p[j] = (short)f2b(o);
                }
                if (ok)
                    *reinterpret_cast<short4v*>((ushort*)C + (size_t)r * 128 + c) = p;
            }
        }
        #pragma unroll
        for (int nn = 0; nn < 4; ++nn)
            #pragma unroll
            for (int j = 0; j < 4; ++j) {
                float a = ps[nn][j], b = ps2[nn][j];
                #pragma unroll
                for (int o2 = 1; o2 < 16; o2 <<= 1) {
                    a += __shfl_xor(a, o2);
                    b += __shfl_xor(b, o2);
                }
                if (rl == 0) {
                    int c = wc + nn * 16 + ch4 + j;
                    atomicAdd(&csum[c], a);
                    atomicAdd(&csum2[c], b);
                }
            }
        __syncthreads();
        if (t < 128) {
            atomicAdd(bn_out + t, csum[t]);
            atomicAdd(bn_out + 128 + t, csum2[t]);
        }
        return;
    }

    // EPI == 0
    #pragma unroll
    for (int m = 0; m < 2; ++m) {
        int r = r0 + wr + m * 16 + rl;
        if (r >= n) continue;
        #pragma unroll
        for (int nn = 0; nn < 4; ++nn) {
            int c = c0 + wc + nn * 16 + ch4;
            f32x4 vacc = acc[m][nn];
            float4 bb = make_float4(0.f, 0.f, 0.f, 0.f);
            if (bias) bb = *reinterpret_cast<const float4*>(bias + c);
            float o0 = vacc[0] + bb.x, o1 = vacc[1] + bb.y;
            float o2 = vacc[2] + bb.z, o3 = vacc[3] + bb.w;
            if (RELU) {
                o0 = fmaxf(o0, 0.f); o1 = fmaxf(o1, 0.f);
                o2 = fmaxf(o2, 0.f); o3 = fmaxf(o3, 0.f);
            }
            short4v p;
            p[0] = (short)f2b(o0); p[1] = (short)f2b(o1);
            p[2] = (short)f2b(o2); p[3] = (short)f2b(o3);
            *reinterpret_cast<short4v*>((ushort*)C + (size_t)r * M + c) = p;
        }
    }
}

// ---------------------------------------------------------------------------
// CSR build
// ---------------------------------------------------------------------------
__global__ void hist_kernel(const int* __restrict__ dst, int* __restrict__ cnt, int E_)
{
    int e = blockIdx.x * blockDim.x + threadIdx.x;
    if (e < E_) atomicAdd(cnt + dst[e], 1);
}

__global__ __launch_bounds__(256) void scan_block_kernel(
    int* __restrict__ data, int* __restrict__ bsum, int n)
{
    __shared__ int tmp[256];
    int i = blockIdx.x * 256 + threadIdx.x;
    int v = (i < n) ? data[i] : 0;
    tmp[threadIdx.x] = v;
    __syncthreads();
    #pragma unroll
    for (int o = 1; o < 256; o <<= 1) {
        int y = (threadIdx.x >= o) ? tmp[threadIdx.x - o] : 0;
        __syncthreads();
        tmp[threadIdx.x] += y;
        __syncthreads();
    }
    if (i < n) data[i] = tmp[threadIdx.x] - v;
    if (threadIdx.x == 255) bsum[blockIdx.x] = tmp[255];
}

__global__ __launch_bounds__(256) void scan_bsum_kernel(int* __restrict__ bsum, int nb)
{
    __shared__ int tmp[256];
    int v = (threadIdx.x < nb) ? bsum[threadIdx.x] : 0;
    tmp[threadIdx.x] = v;
    __syncthreads();
    #pragma unroll
    for (int o = 1; o < 256; o <<= 1) {
        int y = (threadIdx.x >= o) ? tmp[threadIdx.x - o] : 0;
        __syncthreads();
        tmp[threadIdx.x] += y;
        __syncthreads();
    }
    if (threadIdx.x < nb) bsum[threadIdx.x] = tmp[threadIdx.x] - v;
}

__global__ void add_off_kernel(int* __restrict__ data, const int* __restrict__ bsum, int n)
{
    int i = blockIdx.x * blockDim.x + threadIdx.x;
    if (i < n) data[i] += bsum[i >> 8];
}

__global__ void scatter_kernel(const int* __restrict__ src, const int* __restrict__ dst,
                               int* __restrict__ rowptr, int* __restrict__ csr_src, int E_)
{
    int e = blockIdx.x * blockDim.x + threadIdx.x;
    if (e >= E_) return;
    int pos = atomicAdd(rowptr + dst[e], 1);
    csr_src[pos] = src[e];
}

// ---------------------------------------------------------------------------
// Gather attention. One wave per node = 8 edge-slots x 8 lanes.
// Lane owns head hd = lane&7 (ch [16*hd,16*hd+16)) -> QK dot is lane-local.
// QKV interleaved [N][384]: Q at +0, K at +128, V at +256.
// Writes y1 = hsub + wV/z (bf16).
// ---------------------------------------------------------------------------
__global__ __launch_bounds__(256) void attn_agg_kernel(
    const int* __restrict__ rowptr, const int* __restrict__ csr_src,
    const ushort* __restrict__ QKV, const ushort* __restrict__ hsub,
    ushort* __restrict__ out, int n)
{
    int node = (blockIdx.x * blockDim.x + threadIdx.x) >> 6;
    if (node >= n) return;
    int lane = threadIdx.x & 63;
    int slot = lane >> 3;   // 0..7 edge slot
    int hd   = lane & 7;    // head; channels [16*hd, 16*hd+16)
    int start = node ? rowptr[node - 1] : 0;
    int end   = rowptr[node];

    const ushort* qp = QKV + (size_t)node * 384 + hd * 16;
    short8 q0 = *reinterpret_cast<const short8*>(qp);
    short8 q1 = *reinterpret_cast<const short8*>(qp + 8);
    float q[16];
    #pragma unroll
    for (int i = 0; i < 8; ++i) { q[i] = b2f((ushort)q0[i]); q[8 + i] = b2f((ushort)q1[i]); }

    float acc[16] = {};
    float zh = 0.f;
    for (int j = start; j < end; j += 8) {
        int idx  = j + slot;
        bool act = idx < end;
        int s = csr_src[act ? idx : start];
        const ushort* kp = QKV + (size_t)s * 384 + 128 + hd * 16;
        short8 k0 = *reinterpret_cast<const short8*>(kp);
        short8 k1 = *reinterpret_cast<const short8*>(kp + 8);
        float p = 0.f;
        #pragma unroll
        for (int i = 0; i < 8; ++i) {
            p = fmaf(b2f((ushort)k0[i]), q[i], p);
            p = fmaf(b2f((ushort)k1[i]), q[8 + i], p);
        }
        float sc = act ? __expf(fminf(fmaxf(p * 0.25f, -5.f), 5.f)) : 0.f;
        short8 v0 = *reinterpret_cast<const short8*>(kp + 128);
        short8 v1 = *reinterpret_cast<const short8*>(kp + 136);
        #pragma unroll
        for (int i = 0; i < 8; ++i) {
            acc[i]     = fmaf(sc, b2f((ushort)v0[i]), acc[i]);
            acc[8 + i] = fmaf(sc, b2f((ushort)v1[i]), acc[8 + i]);
        }
        zh += sc;
    }
    #pragma unroll
    for (int i = 0; i < 16; ++i) {
        acc[i] += __shfl_xor(acc[i], 8);
        acc[i] += __shfl_xor(acc[i], 16);
        acc[i] += __shfl_xor(acc[i], 32);
    }
    zh += __shfl_xor(zh, 8);
    zh += __shfl_xor(zh, 16);
    zh += __shfl_xor(zh, 32);

    if (slot == 0) {
        const ushort* hp = hsub + (size_t)node * D_ + hd * 16;
        short8 h0 = *reinterpret_cast<const short8*>(hp);
        short8 h1 = *reinterpret_cast<const short8*>(hp + 8);
        float inv = 1.f / zh;
        short8 o0, o1;
        #pragma unroll
        for (int i = 0; i < 8; ++i) {
            o0[i] = (short)f2b(b2f((ushort)h0[i]) + acc[i] * inv);
            o1[i] = (short)f2b(b2f((ushort)h1[i]) + acc[8 + i] * inv);
        }
        ushort* op = out + (size_t)node * D_ + hd * 16;
        *reinterpret_cast<short8*>(op)     = o0;
        *reinterpret_cast<short8*>(op + 8) = o1;
    }
}

// ---------------------------------------------------------------------------
// BN stats over bf16 input: sums[c], sums[128+c].
// ---------------------------------------------------------------------------
__global__ __launch_bounds__(256) void bn_stats_kernel(
    const ushort* __restrict__ x, float* __restrict__ sums, int n)
{
    int c    = threadIdx.x & 127;
    int half = threadIdx.x >> 7;
    float s = 0.f, s2 = 0.f;
    for (int r = blockIdx.x * 2 + half; r < n; r += gridDim.x * 2) {
        float v = b2f(x[(size_t)r * D_ + c]);
        s += v; s2 += v * v;
    }
    __shared__ float ls[256], ls2[256];
    ls[threadIdx.x] = s; ls2[threadIdx.x] = s2;
    __syncthreads();
    if (half == 0) {
        s  += ls[threadIdx.x + 128];
        s2 += ls2[threadIdx.x + 128];
        atomicAdd(sums + c, s);
        atomicAdd(sums + 128 + c, s2);
    }
}

// final BN: bf16 in -> f32 out, 4 elems/thread
__global__ void bn_norm_kernel(const ushort* __restrict__ x,
                               const float* __restrict__ stats,
                               const float* __restrict__ g, const float* __restrict__ b,
                               float* __restrict__ out, float invn, int total4)
{
    int i = blockIdx.x * blockDim.x + threadIdx.x;
    if (i >= total4) return;
    int cb = (i << 2) & 127;
    short4v v = reinterpret_cast<const short4v*>(x)[i];
    float4 o;
    float r[4];
    #pragma unroll
    for (int q = 0; q < 4; ++q) {
        int c = cb + q;
        float m   = stats[c] * invn;
        float var = stats[128 + c] * invn - m * m;
        float rs  = rsqrtf(var + 1e-5f);
        r[q] = (b2f((ushort)v[q]) - m) * rs * g[c] + b[c];
    }
    o.x = r[0]; o.y = r[1]; o.z = r[2]; o.w = r[3];
    reinterpret_cast<float4*>(out)[i] = o;
}

// ---------------------------------------------------------------------------
// Weight prep: Wf = bf16(Wout @ WinV), bfused = Wout @ binV + bout.
// ---------------------------------------------------------------------------
__global__ __launch_bounds__(256) void fuse_w_kernel(
    const float* __restrict__ Win, const float* __restrict__ bin_,
    const float* __restrict__ Wout, const float* __restrict__ bout,
    ushort* __restrict__ Wf, float* __restrict__ bf)
{
    int idx = blockIdx.x * 256 + threadIdx.x;   // 16384 total
    int i = idx >> 7, c = idx & 127;
    const float* WinV = Win + 256 * 128;
    float s = 0.f;
    for (int j = 0; j < 128; ++j)
        s = fmaf(Wout[i * 128 + j], WinV[j * 128 + c], s);
    Wf[idx] = f2b(s);
    if (c == 0) {
        float tb = bout[i];
        for (int j = 0; j < 128; ++j)
            tb = fmaf(Wout[i * 128 + j], bin_[256 + j], tb);
        bf[i] = tb;
    }
}

// bf16 conversion of the 7 remaining weight mats (245760 elems, 4/thread)
struct WPtrs { const float* p[7]; };

__global__ __launch_bounds__(256) void cvt_w_kernel(WPtrs wp, ushort* __restrict__ out)
{
    const int off[8] = {0, 65536, 131072, 147456, 163840, 180224, 212992, 245760};
    int e0 = (blockIdx.x * 256 + threadIdx.x) * 4;
    if (e0 >= 245760) return;
    int s = 0;
    #pragma unroll
    for (int j = 1; j < 7; ++j) if (e0 >= off[j]) s = j;
    float4 f = *reinterpret_cast<const float4*>(wp.p[s] + (e0 - off[s]));
    short4v o;
    o[0] = (short)f2b(f.x); o[1] = (short)f2b(f.y);
    o[2] = (short)f2b(f.z); o[3] = (short)f2b(f.w);
    *reinterpret_cast<short4v*>(out + e0) = o;
}

// ---------------------------------------------------------------------------
extern "C" void kernel_launch(void* const* d_in, const int* in_sizes, int n_in,
                              void* d_out, int out_size, void* d_ws, size_t ws_size,
                              hipStream_t stream)
{
    const float* h    = (const float*)d_in[0];
    const int*   src  = (const int*)d_in[1];
    const int*   dst  = (const int*)d_in[2];
    const float* Win  = (const float*)d_in[3];
    const float* bin_ = (const float*)d_in[4];
    const float* Wout = (const float*)d_in[5];
    const float* bout = (const float*)d_in[6];
    const float* Wte1 = (const float*)d_in[7];
    const float* bte1 = (const float*)d_in[8];
    const float* Wte2 = (const float*)d_in[9];
    const float* bte2 = (const float*)d_in[10];
    const float* ln1g = (const float*)d_in[11];
    const float* ln1b = (const float*)d_in[12];
    const float* ln2g = (const float*)d_in[13];
    const float* ln2b = (const float*)d_in[14];
    const float* WQ   = (const float*)d_in[15];
    const float* WK   = (const float*)d_in[16];
    const float* WV   = (const float*)d_in[17];
    const float* W1   = (const float*)d_in[18];
    const float* b1   = (const float*)d_in[19];
    const float* W2   = (const float*)d_in[20];
    const float* b2   = (const float*)d_in[21];
    const float* bn1g = (const float*)d_in[22];
    const float* bn1b = (const float*)d_in[23];
    const float* bn2g = (const float*)d_in[24];
    const float* bn2b = (const float*)d_in[25];

    const int N_ = in_sizes[0] / D_;
    const int E_ = in_sizes[1];
    const size_t S2 = (size_t)N_ * D_ / 2;   // float-units of one N x 128 bf16 buffer

    float* ws = (float*)d_ws;
    size_t off_tail = 7 * S2;
    size_t need = (off_tail + 131072 + 128 + 512) * sizeof(float)
                + (size_t)(N_ + E_ + 256) * sizeof(int) + 4096;
    if (ws_size < need) return;

    ushort* bufA   = (ushort*)ws;
    ushort* bufB   = (ushort*)(ws + S2);
    ushort* bufC   = (ushort*)(ws + 2 * S2);
    ushort* bufD   = (ushort*)(ws + 3 * S2);          // bf16 Nx512 max
    ushort* wbf    = (ushort*)(ws + off_tail);        // 262144 bf16
    float*  bfused = ws + off_tail + 131072;          // 128
    float*  stats  = bfused + 128;                    // 512
    int* rowptr  = (int*)(stats + 512);               // N
    int* csr_src = rowptr + N_;                       // E
    int* bsum    = csr_src + E_;                      // 256

    const ushort* Wte1_bf = wbf;
    const ushort* Wte2_bf = wbf + 65536;
    const ushort* WQKV_bf = wbf + 131072;             // [WQ;WK;WV] 384x128
    const ushort* W1_bf   = wbf + 180224;
    const ushort* W2_bf   = wbf + 212992;
    ushort*       Wf_bf   = wbf + 245760;             // fused Wout@WinV

    dim3 blk(256);
    dim3 blk512(512);
    const int rowBlocks = (N_ + 127) / 128;
    const int totElems  = N_ * D_;
    const dim3 gRow((N_ + 3) / 4);
    const int nb = (N_ + 255) / 256;
    const float invn = 1.f / (float)N_;

    hipMemsetAsync(stats, 0, 512 * sizeof(float), stream);
    hipMemsetAsync(rowptr, 0, (size_t)N_ * sizeof(int), stream);

    // --- CSR build ---
    hist_kernel<<<dim3((E_ + 255) / 256), blk, 0, stream>>>(dst, rowptr, E_);
    scan_block_kernel<<<dim3(nb), blk, 0, stream>>>(rowptr, bsum, N_);
    scan_bsum_kernel<<<dim3(1), blk, 0, stream>>>(bsum, nb);
    add_off_kernel<<<dim3(nb), blk, 0, stream>>>(rowptr, bsum, N_);
    scatter_kernel<<<dim3((E_ + 255) / 256), blk, 0, stream>>>(src, dst, rowptr, csr_src, E_);

    // --- weight prep ---
    fuse_w_kernel<<<dim3(64), blk, 0, stream>>>(Win, bin_, Wout, bout, Wf_bf, bfused);
    WPtrs wp;
    wp.p[0] = Wte1; wp.p[1] = Wte2; wp.p[2] = WQ; wp.p[3] = WK; wp.p[4] = WV;
    wp.p[5] = W1;   wp.p[6] = W2;
    cvt_w_kernel<<<dim3(240), blk, 0, stream>>>(wp, wbf);

    // --- per-node TransformerEncoder (seq1 attn folded into Wf) ---
    // x = LN1(h + h@Wf^T + bfused)  (LN fused in epilogue)
    gemm_bf16<1, 1, false, true><<<dim3(rowBlocks, 1), blk512, 0, stream>>>(
        h, Wf_bf, bfused, bufA, nullptr, nullptr, nullptr, nullptr,
        h, nullptr, ln1g, ln1b, 0.f, N_, 128, 128);
    // ff1 = relu(x @ Wte1^T + bte1)
    gemm_bf16<0, 0, true, false><<<dim3(rowBlocks, 4), blk512, 0, stream>>>(
        bufA, Wte1_bf, bte1, bufD, nullptr, nullptr, nullptr, nullptr,
        nullptr, nullptr, nullptr, nullptr, 0.f, N_, 128, 512);
    // hsub = LN2(x + ff1 @ Wte2^T + bte2)  (LN fused in epilogue)
    gemm_bf16<0, 1, false, false><<<dim3(rowBlocks, 1), blk512, 0, stream>>>(
        bufD, Wte2_bf, bte2, bufC, nullptr, nullptr, nullptr, nullptr,
        bufA, nullptr, ln2g, ln2b, 0.f, N_, 512, 128);

    // --- graph multi-head attention ---
    gemm_bf16<0, 0, false, false><<<dim3(rowBlocks, 3), blk512, 0, stream>>>(
        bufC, WQKV_bf, nullptr, bufD, nullptr, nullptr, nullptr, nullptr,
        nullptr, nullptr, nullptr, nullptr, 0.f, N_, 128, 384);
    attn_agg_kernel<<<gRow, blk, 0, stream>>>(
        rowptr, csr_src, bufD, bufC, bufA, N_);                          // y1 -> A

    // --- BN1 stats (norm fused into W1 frag-read + W2 epilogue) ---
    bn_stats_kernel<<<dim3(512), blk, 0, stream>>>(bufA, stats, N_);

    // --- FFN + BN2 ---
    // f1 = relu(BN1(y1) @ W1^T + b1)
    gemm_bf16<2, 0, true, false><<<dim3(rowBlocks, 2), blk512, 0, stream>>>(
        bufA, W1_bf, b1, bufD, stats, nullptr, bn1g, bn1b,
        nullptr, nullptr, nullptr, nullptr, invn, N_, 128, 256);
    // y2 = BN1(y1) + f1 @ W2^T + b2 ; BN2 stats fused
    gemm_bf16<0, 2, false, false><<<dim3(rowBlocks, 1), blk512, 0, stream>>>(
        bufD, W2_bf, b2, bufB, stats, stats + 256, bn1g, bn1b,
        nullptr, bufA, nullptr, nullptr, invn, N_, 256, 128);
    bn_norm_kernel<<<dim3((totElems / 4 + 255) / 256), blk, 0, stream>>>(
        bufB, stats + 256, bn2g, bn2b, (float*)d_out, invn, totElems / 4);
}

// Round 8
// 276.108 us; speedup vs baseline: 4.2626x; 1.0248x over previous
//
#include <hip/hip_runtime.h>
#include <hip/hip_bf16.h>

// GraphTransformerLayer on MI355X — round 8: 2-phase GEMM prefetch, merged glue
// kernels, waste-free attention gather. N=50000, E=500000, D=128, H=8, DH=16.

#define D_ 128

typedef __attribute__((ext_vector_type(8))) short short8;
typedef __attribute__((ext_vector_type(4))) short short4v;
typedef __attribute__((ext_vector_type(4))) float f32x4;

__device__ __forceinline__ float b2f(ushort u) {
    union { uint u32; float f; } x; x.u32 = ((uint)u) << 16; return x.f;
}
__device__ __forceinline__ ushort f2b(float f) {
    union { __hip_bfloat16 h; ushort u; } v; v.h = __float2bfloat16(f); return v.u;
}

// ---------------------------------------------------------------------------
// bf16 MFMA GEMM: C[n x M] = A[n x K] @ W[M x K]^T (+bias)(+relu)(+epilogues)
// 512 threads = 8 waves; tile 128x128; wave computes 32x64 (2x4 frags 16x16).
// LDS: double-buffered, [row][chunk^((row>>1)&3)] 16B chunks.
// AMODE 0: A bf16 via global_load_lds, 2-phase prefetch
//       1: A f32 reg-staged with convert (single buffer)
//       2: AMODE0 + BN1 normalize at fragment read (K must be 128)
// EPI   0: bf16 store (+bias,+relu)
//       1: LN(resid + acc + bias) row-norm -> bf16 (M=128, grid.y=1)
//       2: y2 = acc + bias + BN1(y1res) -> bf16 + BN2 stats atomics (M=128)
// ---------------------------------------------------------------------------
template<int AMODE, int EPI, bool RELU, bool RESF32>
__global__ __launch_bounds__(512) void gemm_bf16(
    const void* __restrict__ Aptr, const ushort* __restrict__ W,
    const float* __restrict__ bias, void* __restrict__ C,
    const float* __restrict__ bn_in, float* __restrict__ bn_out,
    const float* __restrict__ bng, const float* __restrict__ bnb,
    const void* __restrict__ resid, const ushort* __restrict__ y1res,
    const float* __restrict__ lng, const float* __restrict__ lnb,
    float invn, int n, int K, int M)
{
    __shared__ ushort Abuf[2][128 * 32];
    __shared__ ushort Bbuf[2][128 * 32];
    __shared__ float s_sh[128], t_sh[128];

    const int t    = threadIdx.x;        // 0..511
    const int lane = t & 63;
    const int w    = t >> 6;             // 0..7
    const int r0   = blockIdx.x * 128;
    const int c0   = blockIdx.y * 128;
    const int wr   = (w >> 1) * 32;
    const int wc   = (w & 1) * 64;
    const int rl   = lane & 15;
    const int kh   = lane >> 4;          // 16B k-chunk 0..3

    if (AMODE == 2 || EPI == 2) {
        if (t < 128) {
            float m   = bn_in[t] * invn;
            float var = bn_in[128 + t] * invn - m * m;
            float rs  = rsqrtf(var + 1e-5f);
            float s   = rs * bng[t];
            s_sh[t] = s;
            t_sh[t] = bnb[t] - m * s;
        }
        __syncthreads();
    }

    f32x4 acc[2][4] = {};
    const int nc = K >> 5;               // 32-wide k-chunks
    const int row = t >> 2, pos = t & 3;

    if (AMODE == 1) {
        // single-buffer reg staging with f32->bf16 convert
        for (int c = 0; c < nc; ++c) {
            int kc = c * 32;
            const int ch = pos;
            int gr = r0 + row;
            short8 aval = {};
            if (gr < n) {
                const float* Af = (const float*)Aptr;
                float4 f0 = *reinterpret_cast<const float4*>(Af + (size_t)gr * K + kc + ch * 8);
                float4 f1 = *reinterpret_cast<const float4*>(Af + (size_t)gr * K + kc + ch * 8 + 4);
                aval[0] = (short)f2b(f0.x); aval[1] = (short)f2b(f0.y);
                aval[2] = (short)f2b(f0.z); aval[3] = (short)f2b(f0.w);
                aval[4] = (short)f2b(f1.x); aval[5] = (short)f2b(f1.y);
                aval[6] = (short)f2b(f1.z); aval[7] = (short)f2b(f1.w);
            }
            short8 bval = *reinterpret_cast<const short8*>(W + (size_t)(c0 + row) * K + kc + ch * 8);
            __syncthreads();
            int sw = ch ^ ((row >> 1) & 3);
            *reinterpret_cast<short8*>(&Abuf[0][row * 32 + sw * 8]) = aval;
            *reinterpret_cast<short8*>(&Bbuf[0][row * 32 + sw * 8]) = bval;
            __syncthreads();
            short8 af[2], bfr[4];
            #pragma unroll
            for (int m = 0; m < 2; ++m) {
                int rr = wr + m * 16 + rl;
                af[m] = *reinterpret_cast<const short8*>(&Abuf[0][rr * 32 + (kh ^ ((rr >> 1) & 3)) * 8]);
            }
            #pragma unroll
            for (int nn = 0; nn < 4; ++nn) {
                int col = wc + nn * 16 + rl;
                bfr[nn] = *reinterpret_cast<const short8*>(&Bbuf[0][col * 32 + (kh ^ ((col >> 1) & 3)) * 8]);
            }
            #pragma unroll
            for (int m = 0; m < 2; ++m)
                #pragma unroll
                for (int nn = 0; nn < 4; ++nn)
                    acc[m][nn] = __builtin_amdgcn_mfma_f32_16x16x32_bf16(
                        bfr[nn], af[m], acc[m][nn], 0, 0, 0);
        }
    } else {
        // 2-phase prefetch: stage c+1 while computing c; one barrier per chunk.
        const int ch = pos ^ ((row >> 1) & 3);   // inverse-swizzled source chunk
        const ushort* Abase = (const ushort*)Aptr + (size_t)(r0 + row) * K + ch * 8;
        const ushort* Bbase = W + (size_t)(c0 + row) * K + ch * 8;
        // prologue: chunk 0 -> half 0
        __builtin_amdgcn_global_load_lds(
            (const __attribute__((address_space(1))) void*)Abase,
            (__attribute__((address_space(3))) void*)&Abuf[0][t * 8], 16, 0, 0);
        __builtin_amdgcn_global_load_lds(
            (const __attribute__((address_space(1))) void*)Bbase,
            (__attribute__((address_space(3))) void*)&Bbuf[0][t * 8], 16, 0, 0);
        __syncthreads();
        for (int c = 0; c < nc; ++c) {
            if (c + 1 < nc) {
                int half = (c + 1) & 1;
                __builtin_amdgcn_global_load_lds(
                    (const __attribute__((address_space(1))) void*)(Abase + (c + 1) * 32),
                    (__attribute__((address_space(3))) void*)&Abuf[half][t * 8], 16, 0, 0);
                __builtin_amdgcn_global_load_lds(
                    (const __attribute__((address_space(1))) void*)(Bbase + (c + 1) * 32),
                    (__attribute__((address_space(3))) void*)&Bbuf[half][t * 8], 16, 0, 0);
            }
            const int cur = c & 1;
            const int kc  = c * 32;
            short8 af[2], bfr[4];
            #pragma unroll
            for (int m = 0; m < 2; ++m) {
                int rr = wr + m * 16 + rl;
                af[m] = *reinterpret_cast<const short8*>(&Abuf[cur][rr * 32 + (kh ^ ((rr >> 1) & 3)) * 8]);
            }
            if (AMODE == 2) {
                #pragma unroll
                for (int m = 0; m < 2; ++m) {
                    short8 v = af[m];
                    #pragma unroll
                    for (int q = 0; q < 8; ++q) {
                        int cch = kc + kh * 8 + q;
                        v[q] = (short)f2b(fmaf(b2f((ushort)v[q]), s_sh[cch], t_sh[cch]));
                    }
                    af[m] = v;
                }
            }
            #pragma unroll
            for (int nn = 0; nn < 4; ++nn) {
                int col = wc + nn * 16 + rl;
                bfr[nn] = *reinterpret_cast<const short8*>(&Bbuf[cur][col * 32 + (kh ^ ((col >> 1) & 3)) * 8]);
            }
            #pragma unroll
            for (int m = 0; m < 2; ++m)
                #pragma unroll
                for (int nn = 0; nn < 4; ++nn)
                    acc[m][nn] = __builtin_amdgcn_mfma_f32_16x16x32_bf16(
                        bfr[nn], af[m], acc[m][nn], 0, 0, 0);
            __syncthreads();   // drains vmcnt(0): c+1 data ready; cur reads done
        }
    }

    const int ch4 = kh * 4;

    if (EPI == 1) {
        __shared__ float lnS[128][2], lnS2[128][2];
        float4 bb[4];
        #pragma unroll
        for (int nn = 0; nn < 4; ++nn)
            bb[nn] = *reinterpret_cast<const float4*>(bias + wc + nn * 16 + ch4);
        #pragma unroll
        for (int m = 0; m < 2; ++m) {
            int r = r0 + wr + m * 16 + rl;
            float s = 0.f, s2 = 0.f;
            #pragma unroll
            for (int nn = 0; nn < 4; ++nn) {
                int c = wc + nn * 16 + ch4;
                float rv[4] = {0.f, 0.f, 0.f, 0.f};
                if (r < n) {
                    if (RESF32) {
                        float4 f = *reinterpret_cast<const float4*>((const float*)resid + (size_t)r * 128 + c);
                        rv[0] = f.x; rv[1] = f.y; rv[2] = f.z; rv[3] = f.w;
                    } else {
                        short4v f = *reinterpret_cast<const short4v*>((const ushort*)resid + (size_t)r * 128 + c);
                        rv[0] = b2f((ushort)f[0]); rv[1] = b2f((ushort)f[1]);
                        rv[2] = b2f((ushort)f[2]); rv[3] = b2f((ushort)f[3]);
                    }
                }
                float bj[4] = {bb[nn].x, bb[nn].y, bb[nn].z, bb[nn].w};
                #pragma unroll
                for (int j = 0; j < 4; ++j) {
                    float o = acc[m][nn][j] + bj[j] + rv[j];
                    acc[m][nn][j] = o;
                    s += o; s2 += o * o;
                }
            }
            s  += __shfl_xor(s, 16);  s  += __shfl_xor(s, 32);
            s2 += __shfl_xor(s2, 16); s2 += __shfl_xor(s2, 32);
            if (kh == 0) {
                lnS[wr + m * 16 + rl][w & 1]  = s;
                lnS2[wr + m * 16 + rl][w & 1] = s2;
            }
        }
        __syncthreads();
        #pragma unroll
        for (int m = 0; m < 2; ++m) {
            int rloc = wr + m * 16 + rl;
            int r = r0 + rloc;
            float S  = lnS[rloc][0] + lnS[rloc][1];
            float S2 = lnS2[rloc][0] + lnS2[rloc][1];
            float mean = S * (1.f / 128.f);
            float var  = S2 * (1.f / 128.f) - mean * mean;
            float rs   = rsqrtf(var + 1e-5f);
            if (r >= n) continue;
            #pragma unroll
            for (int nn = 0; nn < 4; ++nn) {
                int c = wc + nn * 16 + ch4;
                float4 gv = *reinterpret_cast<const float4*>(lng + c);
                float4 bv = *reinterpret_cast<const float4*>(lnb + c);
                float gj[4] = {gv.x, gv.y, gv.z, gv.w};
                float bj[4] = {bv.x, bv.y, bv.z, bv.w};
                short4v p;
                #pragma unroll
                for (int j = 0; j < 4; ++j)
                    p[j] = (short)f2b((acc[m][nn][j] - mean) * rs * gj[j] + bj[j]);
                *reinterpret_cast<short4v*>((ushort*)C + (size_t)r * 128 + c) = p;
            }
        }
        return;
    }

    if (EPI == 2) {
        __shared__ float csum[128], csum2[128];
        if (t < 128) { csum[t] = 0.f; csum2[t] = 0.f; }
        __syncthreads();
        float ps[4][4] = {};
        float ps2[4][4] = {};
        #pragma unroll
        for (int m = 0; m < 2; ++m) {
            int r = r0 + wr + m * 16 + rl;
            bool ok = r < n;
            #pragma unroll
            for (int nn = 0; nn < 4; ++nn) {
                int c = wc + nn * 16 + ch4;
                float4 bb = *reinterpret_cast<const float4*>(bias + c);
                float bj[4] = {bb.x, bb.y, bb.z, bb.w};
                short4v yv = {};
                if (ok) yv = *reinterpret_cast<const short4v*>(y1res + (size_t)r * 128 + c);
                short4v p;
                #pragma unroll
                for (int j = 0; j < 4; ++j) {
                    float o = 0.f;
                    if (ok) {
                        o = acc[m][nn][j] + bj[j]
                          + fmaf(b2f((ushort)yv[j]), s_sh[c + j], t_sh[c + j]);
                    }
                    ps[nn][j] += o; ps2[nn][j] += o * o;
                    p[j] = (short)f2b(o);
                }
                if (ok)
                    *reinterpret_cast<short4v*>((ushort*)C + (size_t)r * 128 + c) = p;
            }
        }
        #pragma unroll
        for (int nn = 0; nn < 4; ++nn)
            #pragma unroll
            for (int j = 0; j < 4; ++j) {
                float a = ps[nn][j], b = ps2[nn][j];
                #pragma unroll
                for (int o2 = 1; o2 < 16; o2 <<= 1) {
                    a += __shfl_xor(a, o2);
                    b += __shfl_xor(b, o2);
                }
                if (rl == 0) {
                    int c = wc + nn * 16 + ch4 + j;
                    atomicAdd(&csum[c], a);
                    atomicAdd(&csum2[c], b);
                }
            }
        __syncthreads();
        if (t < 128) {
            atomicAdd(bn_out + t, csum[t]);
            atomicAdd(bn_out + 128 + t, csum2[t]);
        }
        return;
    }

    // EPI == 0
    #pragma unroll
    for (int m = 0; m < 2; ++m) {
        int r = r0 + wr + m * 16 + rl;
        if (r >= n) continue;
        #pragma unroll
        for (int nn = 0; nn < 4; ++nn) {
            int c = c0 + wc + nn * 16 + ch4;
            f32x4 vacc = acc[m][nn];
            float4 bb = make_float4(0.f, 0.f, 0.f, 0.f);
            if (bias) bb = *reinterpret_cast<const float4*>(bias + c);
            float o0 = vacc[0] + bb.x, o1 = vacc[1] + bb.y;
            float o2 = vacc[2] + bb.z, o3 = vacc[3] + bb.w;
            if (RELU) {
                o0 = fmaxf(o0, 0.f); o1 = fmaxf(o1, 0.f);
                o2 = fmaxf(o2, 0.f); o3 = fmaxf(o3, 0.f);
            }
            short4v p;
            p[0] = (short)f2b(o0); p[1] = (short)f2b(o1);
            p[2] = (short)f2b(o2); p[3] = (short)f2b(o3);
            *reinterpret_cast<short4v*>((ushort*)C + (size_t)r * M + c) = p;
        }
    }
}

// ---------------------------------------------------------------------------
// CSR build
// ---------------------------------------------------------------------------
__global__ void hist_kernel(const int* __restrict__ dst, int* __restrict__ cnt, int E_)
{
    int e = blockIdx.x * blockDim.x + threadIdx.x;
    if (e < E_) atomicAdd(cnt + dst[e], 1);
}

__global__ __launch_bounds__(256) void scan_block_kernel(
    int* __restrict__ data, int* __restrict__ bsum, int n)
{
    __shared__ int tmp[256];
    int i = blockIdx.x * 256 + threadIdx.x;
    int v = (i < n) ? data[i] : 0;
    tmp[threadIdx.x] = v;
    __syncthreads();
    #pragma unroll
    for (int o = 1; o < 256; o <<= 1) {
        int y = (threadIdx.x >= o) ? tmp[threadIdx.x - o] : 0;
        __syncthreads();
        tmp[threadIdx.x] += y;
        __syncthreads();
    }
    if (i < n) data[i] = tmp[threadIdx.x] - v;
    if (threadIdx.x == 255) bsum[blockIdx.x] = tmp[255];
}

// add per-block offset; each block reduces its own prefix of raw bsum (nb<=256)
__global__ __launch_bounds__(256) void add_off_kernel(
    int* __restrict__ data, const int* __restrict__ bsum, int n, int nb)
{
    __shared__ int red[4];
    int b = blockIdx.x;
    int v = (threadIdx.x < b && threadIdx.x < nb) ? bsum[threadIdx.x] : 0;
    #pragma unroll
    for (int o = 1; o < 64; o <<= 1) v += __shfl_xor(v, o);
    if ((threadIdx.x & 63) == 0) red[threadIdx.x >> 6] = v;
    __syncthreads();
    int off = red[0] + red[1] + red[2] + red[3];
    int i = b * 256 + threadIdx.x;
    if (i < n) data[i] += off;
}

__global__ void scatter_kernel(const int* __restrict__ src, const int* __restrict__ dst,
                               int* __restrict__ rowptr, int* __restrict__ csr_src, int E_)
{
    int e = blockIdx.x * blockDim.x + threadIdx.x;
    if (e >= E_) return;
    int pos = atomicAdd(rowptr + dst[e], 1);
    csr_src[pos] = src[e];
}

// ---------------------------------------------------------------------------
// Gather attention. 32 lanes per node = 4 edge-slots x 8 heads.
// Lane owns head hd = lane&7 (ch [16*hd,16*hd+16)) -> QK dot lane-local.
// Inactive slots issue NO loads. QKV interleaved [N][384].
// Writes y1 = hsub + wV/z (bf16).
// ---------------------------------------------------------------------------
__global__ __launch_bounds__(256) void attn_agg_kernel(
    const int* __restrict__ rowptr, const int* __restrict__ csr_src,
    const ushort* __restrict__ QKV, const ushort* __restrict__ hsub,
    ushort* __restrict__ out, int n)
{
    int node  = (blockIdx.x * blockDim.x + threadIdx.x) >> 5;
    int lane5 = threadIdx.x & 31;
    int slot  = lane5 >> 3;   // 0..3
    int hd    = lane5 & 7;    // head; channels [16*hd, 16*hd+16)
    bool valid = node < n;
    int nd = valid ? node : 0;
    int start = (valid && nd) ? rowptr[nd - 1] : 0;
    int end   = valid ? rowptr[nd] : 0;

    const ushort* qp = QKV + (size_t)nd * 384 + hd * 16;
    short8 q0 = *reinterpret_cast<const short8*>(qp);
    short8 q1 = *reinterpret_cast<const short8*>(qp + 8);
    float q[16];
    #pragma unroll
    for (int i = 0; i < 8; ++i) { q[i] = b2f((ushort)q0[i]); q[8 + i] = b2f((ushort)q1[i]); }

    float acc[16] = {};
    float zh = 0.f;
    for (int j = start; j < end; j += 4) {
        int idx = j + slot;
        if (idx < end) {
            int s = csr_src[idx];
            const ushort* kp = QKV + (size_t)s * 384 + 128 + hd * 16;
            short8 k0 = *reinterpret_cast<const short8*>(kp);
            short8 k1 = *reinterpret_cast<const short8*>(kp + 8);
            float p = 0.f;
            #pragma unroll
            for (int i = 0; i < 8; ++i) {
                p = fmaf(b2f((ushort)k0[i]), q[i], p);
                p = fmaf(b2f((ushort)k1[i]), q[8 + i], p);
            }
            float sc = __expf(fminf(fmaxf(p * 0.25f, -5.f), 5.f));
            short8 v0 = *reinterpret_cast<const short8*>(kp + 128);
            short8 v1 = *reinterpret_cast<const short8*>(kp + 136);
            #pragma unroll
            for (int i = 0; i < 8; ++i) {
                acc[i]     = fmaf(sc, b2f((ushort)v0[i]), acc[i]);
                acc[8 + i] = fmaf(sc, b2f((ushort)v1[i]), acc[8 + i]);
            }
            zh += sc;
        }
    }
    #pragma unroll
    for (int i = 0; i < 16; ++i) {
        acc[i] += __shfl_xor(acc[i], 8);
        acc[i] += __shfl_xor(acc[i], 16);
    }
    zh += __shfl_xor(zh, 8);
    zh += __shfl_xor(zh, 16);

    if (slot == 0 && valid) {
        const ushort* hp = hsub + (size_t)nd * D_ + hd * 16;
        short8 h0 = *reinterpret_cast<const short8*>(hp);
        short8 h1 = *reinterpret_cast<const short8*>(hp + 8);
        float inv = 1.f / zh;
        short8 o0, o1;
        #pragma unroll
        for (int i = 0; i < 8; ++i) {
            o0[i] = (short)f2b(b2f((ushort)h0[i]) + acc[i] * inv);
            o1[i] = (short)f2b(b2f((ushort)h1[i]) + acc[8 + i] * inv);
        }
        ushort* op = out + (size_t)nd * D_ + hd * 16;
        *reinterpret_cast<short8*>(op)     = o0;
        *reinterpret_cast<short8*>(op + 8) = o1;
    }
}

// ---------------------------------------------------------------------------
// BN stats over bf16 input: sums[c], sums[128+c].
// ---------------------------------------------------------------------------
__global__ __launch_bounds__(256) void bn_stats_kernel(
    const ushort* __restrict__ x, float* __restrict__ sums, int n)
{
    int c    = threadIdx.x & 127;
    int half = threadIdx.x >> 7;
    float s = 0.f, s2 = 0.f;
    for (int r = blockIdx.x * 2 + half; r < n; r += gridDim.x * 2) {
        float v = b2f(x[(size_t)r * D_ + c]);
        s += v; s2 += v * v;
    }
    __shared__ float ls[256], ls2[256];
    ls[threadIdx.x] = s; ls2[threadIdx.x] = s2;
    __syncthreads();
    if (half == 0) {
        s  += ls[threadIdx.x + 128];
        s2 += ls2[threadIdx.x + 128];
        atomicAdd(sums + c, s);
        atomicAdd(sums + 128 + c, s2);
    }
}

// final BN: bf16 in -> f32 out, 4 elems/thread
__global__ void bn_norm_kernel(const ushort* __restrict__ x,
                               const float* __restrict__ stats,
                               const float* __restrict__ g, const float* __restrict__ b,
                               float* __restrict__ out, float invn, int total4)
{
    int i = blockIdx.x * blockDim.x + threadIdx.x;
    if (i >= total4) return;
    int cb = (i << 2) & 127;
    short4v v = reinterpret_cast<const short4v*>(x)[i];
    float4 o;
    float r[4];
    #pragma unroll
    for (int q = 0; q < 4; ++q) {
        int c = cb + q;
        float m   = stats[c] * invn;
        float var = stats[128 + c] * invn - m * m;
        float rs  = rsqrtf(var + 1e-5f);
        r[q] = (b2f((ushort)v[q]) - m) * rs * g[c] + b[c];
    }
    o.x = r[0]; o.y = r[1]; o.z = r[2]; o.w = r[3];
    reinterpret_cast<float4*>(out)[i] = o;
}

// ---------------------------------------------------------------------------
// Merged weight prep: blocks [0,64) fuse Wf = bf16(Wout@WinV) + bfused;
// blocks [64,304) convert the 7 other weight mats to bf16.
// ---------------------------------------------------------------------------
struct WPtrs { const float* p[7]; };

__global__ __launch_bounds__(256) void prep_w_kernel(
    const float* __restrict__ Win, const float* __restrict__ bin_,
    const float* __restrict__ Wout, const float* __restrict__ bout,
    WPtrs wp, ushort* __restrict__ wbf, float* __restrict__ bfused)
{
    int b = blockIdx.x;
    if (b < 64) {
        int idx = b * 256 + threadIdx.x;   // 16384 total
        int i = idx >> 7, c = idx & 127;
        const float* WinV = Win + 256 * 128;
        float s = 0.f;
        for (int j = 0; j < 128; ++j)
            s = fmaf(Wout[i * 128 + j], WinV[j * 128 + c], s);
        wbf[245760 + idx] = f2b(s);
        if (c == 0) {
            float tb = bout[i];
            for (int j = 0; j < 128; ++j)
                tb = fmaf(Wout[i * 128 + j], bin_[256 + j], tb);
            bfused[i] = tb;
        }
    } else {
        const int off[8] = {0, 65536, 131072, 147456, 163840, 180224, 212992, 245760};
        int e0 = ((b - 64) * 256 + threadIdx.x) * 4;
        if (e0 >= 245760) return;
        int s = 0;
        #pragma unroll
        for (int j = 1; j < 7; ++j) if (e0 >= off[j]) s = j;
        float4 f = *reinterpret_cast<const float4*>(wp.p[s] + (e0 - off[s]));
        short4v o;
        o[0] = (short)f2b(f.x); o[1] = (short)f2b(f.y);
        o[2] = (short)f2b(f.z); o[3] = (short)f2b(f.w);
        *reinterpret_cast<short4v*>(wbf + e0) = o;
    }
}

// ---------------------------------------------------------------------------
extern "C" void kernel_launch(void* const* d_in, const int* in_sizes, int n_in,
                              void* d_out, int out_size, void* d_ws, size_t ws_size,
                              hipStream_t stream)
{
    const float* h    = (const float*)d_in[0];
    const int*   src  = (const int*)d_in[1];
    const int*   dst  = (const int*)d_in[2];
    const float* Win  = (const float*)d_in[3];
    const float* bin_ = (const float*)d_in[4];
    const float* Wout = (const float*)d_in[5];
    const float* bout = (const float*)d_in[6];
    const float* Wte1 = (const float*)d_in[7];
    const float* bte1 = (const float*)d_in[8];
    const float* Wte2 = (const float*)d_in[9];
    const float* bte2 = (const float*)d_in[10];
    const float* ln1g = (const float*)d_in[11];
    const float* ln1b = (const float*)d_in[12];
    const float* ln2g = (const float*)d_in[13];
    const float* ln2b = (const float*)d_in[14];
    const float* WQ   = (const float*)d_in[15];
    const float* WK   = (const float*)d_in[16];
    const float* WV   = (const float*)d_in[17];
    const float* W1   = (const float*)d_in[18];
    const float* b1   = (const float*)d_in[19];
    const float* W2   = (const float*)d_in[20];
    const float* b2   = (const float*)d_in[21];
    const float* bn1g = (const float*)d_in[22];
    const float* bn1b = (const float*)d_in[23];
    const float* bn2g = (const float*)d_in[24];
    const float* bn2b = (const float*)d_in[25];

    const int N_ = in_sizes[0] / D_;
    const int E_ = in_sizes[1];
    const size_t S2 = (size_t)N_ * D_ / 2;   // float-units of one N x 128 bf16 buffer

    float* ws = (float*)d_ws;
    size_t off_tail = 7 * S2;
    size_t need = (off_tail + 131072 + 128 + 512) * sizeof(float)
                + (size_t)(N_ + E_ + 256) * sizeof(int) + 4096;
    if (ws_size < need) return;

    ushort* bufA   = (ushort*)ws;
    ushort* bufB   = (ushort*)(ws + S2);
    ushort* bufC   = (ushort*)(ws + 2 * S2);
    ushort* bufD   = (ushort*)(ws + 3 * S2);          // bf16 Nx512 max
    ushort* wbf    = (ushort*)(ws + off_tail);        // 262144 bf16
    float*  bfused = ws + off_tail + 131072;          // 128
    float*  stats  = bfused + 128;                    // 512
    int* rowptr  = (int*)(stats + 512);               // N (contiguous after stats)
    int* csr_src = rowptr + N_;                       // E
    int* bsum    = csr_src + E_;                      // 256

    const ushort* Wte1_bf = wbf;
    const ushort* Wte2_bf = wbf + 65536;
    const ushort* WQKV_bf = wbf + 131072;             // [WQ;WK;WV] 384x128
    const ushort* W1_bf   = wbf + 180224;
    const ushort* W2_bf   = wbf + 212992;
    ushort*       Wf_bf   = wbf + 245760;             // fused Wout@WinV

    dim3 blk(256);
    dim3 blk512(512);
    const int rowBlocks = (N_ + 127) / 128;
    const int totElems  = N_ * D_;
    const dim3 gNode((N_ + 7) / 8);                   // 8 nodes/block (32 lanes/node)
    const int nb = (N_ + 255) / 256;
    const float invn = 1.f / (float)N_;

    // single memset: stats (512 f) + rowptr (N ints) are contiguous
    hipMemsetAsync(stats, 0, (512 + (size_t)N_) * sizeof(float), stream);

    // --- CSR build ---
    hist_kernel<<<dim3((E_ + 255) / 256), blk, 0, stream>>>(dst, rowptr, E_);
    scan_block_kernel<<<dim3(nb), blk, 0, stream>>>(rowptr, bsum, N_);
    add_off_kernel<<<dim3(nb), blk, 0, stream>>>(rowptr, bsum, N_, nb);
    scatter_kernel<<<dim3((E_ + 255) / 256), blk, 0, stream>>>(src, dst, rowptr, csr_src, E_);

    // --- weight prep (merged) ---
    WPtrs wp;
    wp.p[0] = Wte1; wp.p[1] = Wte2; wp.p[2] = WQ; wp.p[3] = WK; wp.p[4] = WV;
    wp.p[5] = W1;   wp.p[6] = W2;
    prep_w_kernel<<<dim3(304), blk, 0, stream>>>(Win, bin_, Wout, bout, wp, wbf, bfused);

    // --- per-node TransformerEncoder (seq1 attn folded into Wf) ---
    gemm_bf16<1, 1, false, true><<<dim3(rowBlocks, 1), blk512, 0, stream>>>(
        h, Wf_bf, bfused, bufA, nullptr, nullptr, nullptr, nullptr,
        h, nullptr, ln1g, ln1b, 0.f, N_, 128, 128);
    gemm_bf16<0, 0, true, false><<<dim3(rowBlocks, 4), blk512, 0, stream>>>(
        bufA, Wte1_bf, bte1, bufD, nullptr, nullptr, nullptr, nullptr,
        nullptr, nullptr, nullptr, nullptr, 0.f, N_, 128, 512);
    gemm_bf16<0, 1, false, false><<<dim3(rowBlocks, 1), blk512, 0, stream>>>(
        bufD, Wte2_bf, bte2, bufC, nullptr, nullptr, nullptr, nullptr,
        bufA, nullptr, ln2g, ln2b, 0.f, N_, 512, 128);

    // --- graph multi-head attention ---
    gemm_bf16<0, 0, false, false><<<dim3(rowBlocks, 3), blk512, 0, stream>>>(
        bufC, WQKV_bf, nullptr, bufD, nullptr, nullptr, nullptr, nullptr,
        nullptr, nullptr, nullptr, nullptr, 0.f, N_, 128, 384);
    attn_agg_kernel<<<gNode, blk, 0, stream>>>(
        rowptr, csr_src, bufD, bufC, bufA, N_);                          // y1 -> A

    // --- BN1 stats (norm fused into W1 frag-read + W2 epilogue) ---
    bn_stats_kernel<<<dim3(512), blk, 0, stream>>>(bufA, stats, N_);

    // --- FFN + BN2 ---
    gemm_bf16<2, 0, true, false><<<dim3(rowBlocks, 2), blk512, 0, stream>>>(
        bufA, W1_bf, b1, bufD, stats, nullptr, bn1g, bn1b,
        nullptr, nullptr, nullptr, nullptr, invn, N_, 128, 256);
    gemm_bf16<0, 2, false, false><<<dim3(rowBlocks, 1), blk512, 0, stream>>>(
        bufD, W2_bf, b2, bufB, stats, stats + 256, bn1g, bn1b,
        nullptr, bufA, nullptr, nullptr, invn, N_, 256, 128);
    bn_norm_kernel<<<dim3((totElems / 4 + 255) / 256), blk, 0, stream>>>(
        bufB, stats + 256, bn2g, bn2b, (float*)d_out, invn, totElems / 4);
}